// Round 3
// baseline (2841.758 us; speedup 1.0000x reference)
//
#include <hip/hip_runtime.h>
#include <math.h>

#define N_NODES 100000
#define N_EDGES 1600000
#define NBUCKET 782            // ceil(N_NODES/128)

// ---------------- degree count ----------------

__global__ void count_deg_kernel(const int* __restrict__ dst, int* __restrict__ counts) {
    int e = blockIdx.x * 256 + threadIdx.x;
    if (e < N_EDGES) atomicAdd(&counts[dst[e]], 1);
}

__global__ void compute_deg_kernel(const int* __restrict__ counts,
                                   float* __restrict__ dis) {
    int i = blockIdx.x * 256 + threadIdx.x;
    if (i < N_NODES) {
        float deg = (float)(counts[i] + 1);   // self-loop
        dis[i] = rsqrtf(deg);
    }
}

// ---------------- prefix scan (rowstart) ----------------

__global__ void scanA_kernel(const int* __restrict__ counts, int* __restrict__ rowstart,
                             int* __restrict__ bsums) {
    __shared__ int s[256];
    int i = blockIdx.x * 256 + threadIdx.x;
    int v = (i < N_NODES) ? counts[i] : 0;
    s[threadIdx.x] = v;
    __syncthreads();
    for (int off = 1; off < 256; off <<= 1) {
        int t = 0;
        if (threadIdx.x >= off) t = s[threadIdx.x - off];
        __syncthreads();
        s[threadIdx.x] += t;
        __syncthreads();
    }
    if (i < N_NODES) rowstart[i] = s[threadIdx.x] - v;
    if (threadIdx.x == 255) bsums[blockIdx.x] = s[255];
}

__global__ void scanB_kernel(int* __restrict__ bsums, int nb) {
    __shared__ int s[512];
    int t = threadIdx.x;
    int v = (t < nb) ? bsums[t] : 0;
    s[t] = v;
    __syncthreads();
    for (int off = 1; off < 512; off <<= 1) {
        int u = 0;
        if (t >= off) u = s[t - off];
        __syncthreads();
        s[t] += u;
        __syncthreads();
    }
    if (t < nb) bsums[t] = s[t] - v;
}

__global__ void scanC_kernel(int* __restrict__ rowstart, const int* __restrict__ bsums) {
    int i = blockIdx.x * 256 + threadIdx.x;
    if (i < N_NODES) rowstart[i] += bsums[blockIdx.x];
}

// ---------------- CSR fill, two-phase bucket scatter ----------------

__global__ void init_bcur_kernel(const int* __restrict__ rowstart, int* __restrict__ bcur) {
    int b = blockIdx.x * 256 + threadIdx.x;
    if (b < NBUCKET) bcur[b] = rowstart[b * 128];
}

// Phase A: coarse-bucket edges by dst>>7; per-bucket write streams are sequential.
__global__ void csr_phaseA_kernel(const int* __restrict__ src, const int* __restrict__ dst,
                                  int* __restrict__ bcur, int2* __restrict__ pairs) {
    int e = blockIdx.x * 256 + threadIdx.x;
    if (e < N_EDGES) {
        int d = dst[e];
        int pos = atomicAdd(&bcur[d >> 7], 1);
        pairs[pos] = make_int2(src[e], d);
    }
}

// Phase B: one block per bucket; LDS per-node cursors; writes land in a hot 8KB region.
__global__ __launch_bounds__(256) void csr_phaseB_kernel(const int2* __restrict__ pairs,
                                                         const int* __restrict__ rowstart,
                                                         int* __restrict__ csr_src) {
    __shared__ int lcur[128];
    int b = blockIdx.x;
    int node_base = b * 128;
    if (threadIdx.x < 128) {
        int node = node_base + threadIdx.x;
        lcur[threadIdx.x] = (node < N_NODES) ? rowstart[node] : 0;
    }
    __syncthreads();
    int region_start = rowstart[node_base];
    int nb2 = node_base + 128;
    int region_end = (nb2 < N_NODES) ? rowstart[nb2] : N_EDGES;
    for (int e = region_start + threadIdx.x; e < region_end; e += 256) {
        int2 p = pairs[e];
        int pos = atomicAdd(&lcur[p.y - node_base], 1);
        csr_src[pos] = p.x;
    }
}

// ---------------- GEMM: Yb[16][N][8] = (X[N,128] @ W[128,128]) * scale[row] ----------------
// 128x128 tile, 256 threads, 8x8 micro-tile, A transposed in LDS, blocked output.

__global__ __launch_bounds__(256) void gemm128b_kernel(const float* __restrict__ X,
                                                       const float* __restrict__ W,
                                                       const float* __restrict__ scale,
                                                       float* __restrict__ Yb, int nrows) {
    __shared__ float As[16][132];   // [k][row]
    __shared__ float Bs[16][128];   // [k][col]
    int tid = threadIdx.x;
    int tx = tid & 15;    // col block: cols tx*8..+8  (== output slice tx)
    int ty = tid >> 4;    // row block: rows ty*8..+8
    int rowBase = blockIdx.x * 128;

    float acc[8][8];
#pragma unroll
    for (int i = 0; i < 8; i++)
#pragma unroll
        for (int j = 0; j < 8; j++) acc[i][j] = 0.f;

    int a_r  = tid >> 1;          // 0..127
    int a_k4 = (tid & 1) * 8;     // 0 or 8

    for (int kb = 0; kb < 128; kb += 16) {
        // A tile: rows rowBase..+128, k kb..+16 (transposed store)
        {
            int grow = rowBase + a_r;
            float4 v0 = make_float4(0.f,0.f,0.f,0.f), v1 = v0;
            if (grow < nrows) {
                v0 = *(const float4*)&X[(size_t)grow * 128 + kb + a_k4];
                v1 = *(const float4*)&X[(size_t)grow * 128 + kb + a_k4 + 4];
            }
            As[a_k4 + 0][a_r] = v0.x; As[a_k4 + 1][a_r] = v0.y;
            As[a_k4 + 2][a_r] = v0.z; As[a_k4 + 3][a_r] = v0.w;
            As[a_k4 + 4][a_r] = v1.x; As[a_k4 + 5][a_r] = v1.y;
            As[a_k4 + 6][a_r] = v1.z; As[a_k4 + 7][a_r] = v1.w;
        }
        // B tile: 16x128, two float4 per thread
        {
            int f0 = tid, f1 = tid + 256;
            *(float4*)&Bs[f0 >> 5][(f0 & 31) * 4] =
                *(const float4*)&W[(size_t)(kb + (f0 >> 5)) * 128 + (f0 & 31) * 4];
            *(float4*)&Bs[f1 >> 5][(f1 & 31) * 4] =
                *(const float4*)&W[(size_t)(kb + (f1 >> 5)) * 128 + (f1 & 31) * 4];
        }
        __syncthreads();
#pragma unroll
        for (int kk = 0; kk < 16; kk++) {
            float4 a0 = *(const float4*)&As[kk][ty * 8];
            float4 a1 = *(const float4*)&As[kk][ty * 8 + 4];
            float4 b0 = *(const float4*)&Bs[kk][tx * 8];
            float4 b1 = *(const float4*)&Bs[kk][tx * 8 + 4];
            float a[8] = {a0.x,a0.y,a0.z,a0.w,a1.x,a1.y,a1.z,a1.w};
            float b[8] = {b0.x,b0.y,b0.z,b0.w,b1.x,b1.y,b1.z,b1.w};
#pragma unroll
            for (int i = 0; i < 8; i++)
#pragma unroll
                for (int j = 0; j < 8; j++) acc[i][j] = fmaf(a[i], b[j], acc[i][j]);
        }
        __syncthreads();
    }
    // epilogue: slice tx, rows ty*8..+8, pre-scale by dis
#pragma unroll
    for (int i = 0; i < 8; i++) {
        int grow = rowBase + ty * 8 + i;
        if (grow < nrows) {
            float s = scale[grow];
            float* dp = &Yb[((size_t)tx * N_NODES + grow) * 8];
            float4 o0 = make_float4(acc[i][0]*s, acc[i][1]*s, acc[i][2]*s, acc[i][3]*s);
            float4 o1 = make_float4(acc[i][4]*s, acc[i][5]*s, acc[i][6]*s, acc[i][7]*s);
            *(float4*)dp = o0;
            *(float4*)(dp + 4) = o1;
        }
    }
}

// ---------------- XCD-sharded aggregation ----------------
// Slice s (8 channels) processed only by XCD (s&7): its 3.2MB slab stays L2-resident.
// out[n][ch] = relu( b[ch] + dis[n] * (Hb[s][n][c] + sum_src Hb[s][src][c]) )
// Lane layout: lane = g*8+c; 8 edges (g) x 8 channels (c) per gather instruction.

#define AGG_NPB 64

__global__ __launch_bounds__(256) void aggregate_xcd_kernel(const float* __restrict__ Hb,
                                                            const float* __restrict__ dis,
                                                            const int* __restrict__ rowstart,
                                                            const int* __restrict__ counts,
                                                            const int* __restrict__ csr_src,
                                                            const float* __restrict__ bias,
                                                            float* __restrict__ Out,
                                                            int slice_base) {
    int s_local = blockIdx.x & 7;
    int chunk   = blockIdx.x >> 3;
    int s = slice_base + s_local;
    const float* __restrict__ H = Hb + (size_t)s * N_NODES * 8;
    int wave = threadIdx.x >> 6;
    int lane = threadIdx.x & 63;
    int g = lane >> 3;
    int c = lane & 7;
    float bc = bias[s * 8 + c];

    for (int ni = wave; ni < AGG_NPB; ni += 4) {
        int n = chunk * AGG_NPB + ni;
        if (n >= N_NODES) break;
        int start = __builtin_nontemporal_load(&rowstart[n]);
        int cnt   = __builtin_nontemporal_load(&counts[n]);
        float acc = 0.f;
        int end = start + cnt;
        for (int j = start + g; j < end; j += 8) {
            int srcid = __builtin_nontemporal_load(&csr_src[j]);
            acc += H[(size_t)srcid * 8 + c];      // cached: slice resident in this XCD's L2
        }
        acc += __shfl_xor(acc, 8);
        acc += __shfl_xor(acc, 16);
        acc += __shfl_xor(acc, 32);
        float own = H[(size_t)n * 8 + c];
        float dn  = __builtin_nontemporal_load(&dis[n]);
        float r = fmaxf(fmaf(dn, acc + own, bc), 0.f);
        if (g == 0)
            __builtin_nontemporal_store(r, &Out[(size_t)n * 128 + s * 8 + c]);
    }
}

// ---------------- Final: out = sigmoid(H @ Wr + br)*0.8 + 0.1 ----------------

__global__ __launch_bounds__(256) void final_kernel(const float* __restrict__ H,
                                                    const float* __restrict__ Wr,
                                                    const float* __restrict__ br,
                                                    float* __restrict__ out) {
    __shared__ float hs[16][132];
    __shared__ float ws[128][16];
    int tid = threadIdx.x;
    int rowBase = blockIdx.x * 16;
    {
        int k  = tid & 127;
        int r0 = tid >> 7;
#pragma unroll
        for (int rr = 0; rr < 8; rr++) {
            int r = r0 + rr * 2;
            int grow = rowBase + r;
            hs[r][k] = (grow < N_NODES) ? H[(size_t)grow * 128 + k] : 0.f;
        }
#pragma unroll
        for (int q = 0; q < 8; q++) {
            int idx = q * 256 + tid;
            ws[idx >> 4][idx & 15] = Wr[idx];
        }
    }
    __syncthreads();
    int row = tid >> 4;
    int c   = tid & 15;
    float acc = br[c];
#pragma unroll
    for (int k = 0; k < 128; k++)
        acc = fmaf(hs[row][k], ws[k][c], acc);
    int grow = rowBase + row;
    if (grow < N_NODES) {
        float sg = 1.f / (1.f + expf(-acc));
        out[(size_t)grow * 16 + c] = 0.8f * sg + 0.1f;
    }
}

// ---------------- Launch ----------------

extern "C" void kernel_launch(void* const* d_in, const int* in_sizes, int n_in,
                              void* d_out, int out_size, void* d_ws, size_t ws_size,
                              hipStream_t stream) {
    const float* x  = (const float*)d_in[0];
    const int*   ei = (const int*)d_in[1];
    const int*   src = ei;
    const int*   dst = ei + N_EDGES;
    const float* W0 = (const float*)d_in[2];
    const float* b0 = (const float*)d_in[3];
    const float* W1 = (const float*)d_in[4];
    const float* b1 = (const float*)d_in[5];
    const float* W2 = (const float*)d_in[6];
    const float* b2 = (const float*)d_in[7];
    const float* Wr = (const float*)d_in[8];
    const float* br = (const float*)d_in[9];
    float* out = (float*)d_out;

    char* ws = (char*)d_ws;
    size_t off = 0;
    auto take = [&](size_t bytes) {
        char* p = ws + off;
        off += (bytes + 255) & ~(size_t)255;
        return p;
    };
    float* hA      = (float*)take((size_t)N_NODES * 128 * 4);  // agg out (normal layout)
    float* hBb     = (float*)take((size_t)N_NODES * 128 * 4);  // gemm out (blocked [16][N][8])
    int*   counts  = (int*)take((size_t)N_NODES * 4);
    int*   rowstart= (int*)take((size_t)N_NODES * 4);
    float* dis     = (float*)take((size_t)N_NODES * 4);
    int*   csr_src = (int*)take((size_t)N_EDGES * 4);
    int*   bcur    = (int*)take(1024 * 4);
    int*   bsums   = (int*)take(1024 * 4);
    // pairs buffer overlays hA: dead before first aggregate writes hA
    int2*  pairs   = (int2*)hA;
    (void)ws_size; (void)in_sizes; (void)n_in; (void)out_size;

    hipMemsetAsync(counts, 0, (size_t)N_NODES * 4, stream);

    int nbE = (N_EDGES + 255) / 256;   // 6250
    int nbN = (N_NODES + 255) / 256;   // 391

    count_deg_kernel<<<nbE, 256, 0, stream>>>(dst, counts);
    compute_deg_kernel<<<nbN, 256, 0, stream>>>(counts, dis);
    scanA_kernel<<<nbN, 256, 0, stream>>>(counts, rowstart, bsums);
    scanB_kernel<<<1, 512, 0, stream>>>(bsums, nbN);
    scanC_kernel<<<nbN, 256, 0, stream>>>(rowstart, bsums);
    init_bcur_kernel<<<(NBUCKET + 255) / 256, 256, 0, stream>>>(rowstart, bcur);
    csr_phaseA_kernel<<<nbE, 256, 0, stream>>>(src, dst, bcur, pairs);
    csr_phaseB_kernel<<<NBUCKET, 256, 0, stream>>>(pairs, rowstart, csr_src);

    const float* Wl[3] = {W0, W1, W2};
    const float* bl[3] = {b0, b1, b2};
    const float* hin = x;
    int aggBlocks = ((N_NODES + AGG_NPB - 1) / AGG_NPB) * 8;   // 12504
    for (int l = 0; l < 3; l++) {
        gemm128b_kernel<<<(N_NODES + 127) / 128, 256, 0, stream>>>(hin, Wl[l], dis, hBb, N_NODES);
        aggregate_xcd_kernel<<<aggBlocks, 256, 0, stream>>>(hBb, dis, rowstart, counts,
                                                            csr_src, bl[l], hA, 0);
        aggregate_xcd_kernel<<<aggBlocks, 256, 0, stream>>>(hBb, dis, rowstart, counts,
                                                            csr_src, bl[l], hA, 8);
        hin = hA;
    }
    final_kernel<<<N_NODES / 16, 256, 0, stream>>>(hA, Wr, br, out);
}

// Round 4
// 812.065 us; speedup vs baseline: 3.4994x; 3.4994x over previous
//
#include <hip/hip_runtime.h>
#include <math.h>

#define N_NODES 100000
#define N_EDGES 1600000

// ---------------- degree count ----------------

__global__ void count_deg_kernel(const int* __restrict__ dst, int* __restrict__ counts) {
    int e = blockIdx.x * 256 + threadIdx.x;
    if (e < N_EDGES) atomicAdd(&counts[dst[e]], 1);
}

__global__ void compute_deg_kernel(const int* __restrict__ counts,
                                   float* __restrict__ dis) {
    int i = blockIdx.x * 256 + threadIdx.x;
    if (i < N_NODES) {
        float deg = (float)(counts[i] + 1);   // self-loop
        dis[i] = rsqrtf(deg);
    }
}

// ---------------- prefix scan (rowstart) ----------------

__global__ void scanA_kernel(const int* __restrict__ counts, int* __restrict__ rowstart,
                             int* __restrict__ bsums) {
    __shared__ int s[256];
    int i = blockIdx.x * 256 + threadIdx.x;
    int v = (i < N_NODES) ? counts[i] : 0;
    s[threadIdx.x] = v;
    __syncthreads();
    for (int off = 1; off < 256; off <<= 1) {
        int t = 0;
        if (threadIdx.x >= off) t = s[threadIdx.x - off];
        __syncthreads();
        s[threadIdx.x] += t;
        __syncthreads();
    }
    if (i < N_NODES) rowstart[i] = s[threadIdx.x] - v;
    if (threadIdx.x == 255) bsums[blockIdx.x] = s[255];
}

__global__ void scanB_kernel(int* __restrict__ bsums, int nb) {
    __shared__ int s[512];
    int t = threadIdx.x;
    int v = (t < nb) ? bsums[t] : 0;
    s[t] = v;
    __syncthreads();
    for (int off = 1; off < 512; off <<= 1) {
        int u = 0;
        if (t >= off) u = s[t - off];
        __syncthreads();
        s[t] += u;
        __syncthreads();
    }
    if (t < nb) bsums[t] = s[t] - v;
}

__global__ void scanC_kernel(int* __restrict__ rowstart, const int* __restrict__ bsums) {
    int i = blockIdx.x * 256 + threadIdx.x;
    if (i < N_NODES) rowstart[i] += bsums[blockIdx.x];
}

// ---------------- CSR fill (direct per-node cursor; measured 122us in r2) ----------------

__global__ void csr_fill_kernel(const int* __restrict__ src, const int* __restrict__ dst,
                                const int* __restrict__ rowstart, int* __restrict__ cursor,
                                int* __restrict__ csr_src) {
    int e = blockIdx.x * 256 + threadIdx.x;
    if (e < N_EDGES) {
        int d = dst[e];
        int pos = rowstart[d] + atomicAdd(&cursor[d], 1);
        __builtin_nontemporal_store(src[e], &csr_src[pos]);
    }
}

// ---------------- GEMM: Y[N,128] = (X[N,128] @ W[128,128]) * scale[row] ----------------
// 128x128 tile, 256 threads, 8x8 micro-tile, A transposed in LDS.

__global__ __launch_bounds__(256) void gemm128_kernel(const float* __restrict__ X,
                                                      const float* __restrict__ W,
                                                      const float* __restrict__ scale,
                                                      float* __restrict__ Y, int nrows) {
    __shared__ float As[16][132];   // [k][row]
    __shared__ float Bs[16][128];   // [k][col]
    int tid = threadIdx.x;
    int tx = tid & 15;    // col block: cols tx*8..+8
    int ty = tid >> 4;    // row block: rows ty*8..+8
    int rowBase = blockIdx.x * 128;

    float acc[8][8];
#pragma unroll
    for (int i = 0; i < 8; i++)
#pragma unroll
        for (int j = 0; j < 8; j++) acc[i][j] = 0.f;

    int a_r  = tid >> 1;          // 0..127
    int a_k4 = (tid & 1) * 8;     // 0 or 8

    for (int kb = 0; kb < 128; kb += 16) {
        // A tile: rows rowBase..+128, k kb..+16 (transposed store)
        {
            int grow = rowBase + a_r;
            float4 v0 = make_float4(0.f,0.f,0.f,0.f), v1 = v0;
            if (grow < nrows) {
                v0 = *(const float4*)&X[(size_t)grow * 128 + kb + a_k4];
                v1 = *(const float4*)&X[(size_t)grow * 128 + kb + a_k4 + 4];
            }
            As[a_k4 + 0][a_r] = v0.x; As[a_k4 + 1][a_r] = v0.y;
            As[a_k4 + 2][a_r] = v0.z; As[a_k4 + 3][a_r] = v0.w;
            As[a_k4 + 4][a_r] = v1.x; As[a_k4 + 5][a_r] = v1.y;
            As[a_k4 + 6][a_r] = v1.z; As[a_k4 + 7][a_r] = v1.w;
        }
        // B tile: 16x128, two float4 per thread
        {
            int f0 = tid, f1 = tid + 256;
            *(float4*)&Bs[f0 >> 5][(f0 & 31) * 4] =
                *(const float4*)&W[(size_t)(kb + (f0 >> 5)) * 128 + (f0 & 31) * 4];
            *(float4*)&Bs[f1 >> 5][(f1 & 31) * 4] =
                *(const float4*)&W[(size_t)(kb + (f1 >> 5)) * 128 + (f1 & 31) * 4];
        }
        __syncthreads();
#pragma unroll
        for (int kk = 0; kk < 16; kk++) {
            float4 a0 = *(const float4*)&As[kk][ty * 8];
            float4 a1 = *(const float4*)&As[kk][ty * 8 + 4];
            float4 b0 = *(const float4*)&Bs[kk][tx * 8];
            float4 b1 = *(const float4*)&Bs[kk][tx * 8 + 4];
            float a[8] = {a0.x,a0.y,a0.z,a0.w,a1.x,a1.y,a1.z,a1.w};
            float b[8] = {b0.x,b0.y,b0.z,b0.w,b1.x,b1.y,b1.z,b1.w};
#pragma unroll
            for (int i = 0; i < 8; i++)
#pragma unroll
                for (int j = 0; j < 8; j++) acc[i][j] = fmaf(a[i], b[j], acc[i][j]);
        }
        __syncthreads();
    }
    // epilogue: rows ty*8..+8, cols tx*8..+8, pre-scale by dis; row-major output
#pragma unroll
    for (int i = 0; i < 8; i++) {
        int grow = rowBase + ty * 8 + i;
        if (grow < nrows) {
            float s = scale[grow];
            float4 o0 = make_float4(acc[i][0]*s, acc[i][1]*s, acc[i][2]*s, acc[i][3]*s);
            float4 o1 = make_float4(acc[i][4]*s, acc[i][5]*s, acc[i][6]*s, acc[i][7]*s);
            *(float4*)&Y[(size_t)grow * 128 + tx * 8]     = o0;
            *(float4*)&Y[(size_t)grow * 128 + tx * 8 + 4] = o1;
        }
    }
}

// ---------------- Aggregation (r2 structure, 8-deep MLP) ----------------
// Hs[i] = h[i]*dis[i] (pre-scaled by GEMM epilogue).
// out[i] = relu( b + dis[i] * (Hs[i] + sum_{e:dst=i} Hs[src]) )
// One wave per node; lane owns 2 channels -> each gather is one 512B coalesced row.

__global__ __launch_bounds__(256) void aggregate_kernel(const float* __restrict__ Hs,
                                                        const float* __restrict__ dis,
                                                        const int* __restrict__ rowstart,
                                                        const int* __restrict__ counts,
                                                        const int* __restrict__ csr_src,
                                                        const float* __restrict__ bias,
                                                        float* __restrict__ Out) {
    int node = blockIdx.x * 4 + (threadIdx.x >> 6);
    node = __builtin_amdgcn_readfirstlane(node);   // wave-uniform -> scalar loads
    int lane = threadIdx.x & 63;
    if (node >= N_NODES) return;
    int c0 = lane * 2;

    float2 own = *(const float2*)&Hs[(size_t)node * 128 + c0];
    float accx = own.x, accy = own.y;

    int start = rowstart[node];
    int cnt   = counts[node];
    int end = start + cnt;
    int j = start;

    // 8 independent 512B row-gathers in flight
    for (; j + 7 < end; j += 8) {
        int s0 = csr_src[j];
        int s1 = csr_src[j + 1];
        int s2 = csr_src[j + 2];
        int s3 = csr_src[j + 3];
        int s4 = csr_src[j + 4];
        int s5 = csr_src[j + 5];
        int s6 = csr_src[j + 6];
        int s7 = csr_src[j + 7];
        float2 v0 = *(const float2*)&Hs[(size_t)s0 * 128 + c0];
        float2 v1 = *(const float2*)&Hs[(size_t)s1 * 128 + c0];
        float2 v2 = *(const float2*)&Hs[(size_t)s2 * 128 + c0];
        float2 v3 = *(const float2*)&Hs[(size_t)s3 * 128 + c0];
        float2 v4 = *(const float2*)&Hs[(size_t)s4 * 128 + c0];
        float2 v5 = *(const float2*)&Hs[(size_t)s5 * 128 + c0];
        float2 v6 = *(const float2*)&Hs[(size_t)s6 * 128 + c0];
        float2 v7 = *(const float2*)&Hs[(size_t)s7 * 128 + c0];
        accx += ((v0.x + v1.x) + (v2.x + v3.x)) + ((v4.x + v5.x) + (v6.x + v7.x));
        accy += ((v0.y + v1.y) + (v2.y + v3.y)) + ((v4.y + v5.y) + (v6.y + v7.y));
    }
    for (; j + 1 < end; j += 2) {
        int s0 = csr_src[j];
        int s1 = csr_src[j + 1];
        float2 v0 = *(const float2*)&Hs[(size_t)s0 * 128 + c0];
        float2 v1 = *(const float2*)&Hs[(size_t)s1 * 128 + c0];
        accx += v0.x + v1.x;
        accy += v0.y + v1.y;
    }
    if (j < end) {
        int s0 = csr_src[j];
        float2 v0 = *(const float2*)&Hs[(size_t)s0 * 128 + c0];
        accx += v0.x;
        accy += v0.y;
    }

    float dsi = dis[node];
    float2 bb = *(const float2*)&bias[c0];
    float2 r;
    r.x = fmaxf(fmaf(accx, dsi, bb.x), 0.f);
    r.y = fmaxf(fmaf(accy, dsi, bb.y), 0.f);
    *(float2*)&Out[(size_t)node * 128 + c0] = r;
}

// ---------------- Final: out = sigmoid(H @ Wr + br)*0.8 + 0.1 ----------------

__global__ __launch_bounds__(256) void final_kernel(const float* __restrict__ H,
                                                    const float* __restrict__ Wr,
                                                    const float* __restrict__ br,
                                                    float* __restrict__ out) {
    __shared__ float hs[16][132];
    __shared__ float ws[128][16];
    int tid = threadIdx.x;
    int rowBase = blockIdx.x * 16;
    {
        int k  = tid & 127;
        int r0 = tid >> 7;
#pragma unroll
        for (int rr = 0; rr < 8; rr++) {
            int r = r0 + rr * 2;
            int grow = rowBase + r;
            hs[r][k] = (grow < N_NODES) ? H[(size_t)grow * 128 + k] : 0.f;
        }
#pragma unroll
        for (int q = 0; q < 8; q++) {
            int idx = q * 256 + tid;
            ws[idx >> 4][idx & 15] = Wr[idx];
        }
    }
    __syncthreads();
    int row = tid >> 4;
    int c   = tid & 15;
    float acc = br[c];
#pragma unroll
    for (int k = 0; k < 128; k++)
        acc = fmaf(hs[row][k], ws[k][c], acc);
    int grow = rowBase + row;
    if (grow < N_NODES) {
        float sg = 1.f / (1.f + expf(-acc));
        out[(size_t)grow * 16 + c] = 0.8f * sg + 0.1f;
    }
}

// ---------------- Launch ----------------

extern "C" void kernel_launch(void* const* d_in, const int* in_sizes, int n_in,
                              void* d_out, int out_size, void* d_ws, size_t ws_size,
                              hipStream_t stream) {
    const float* x  = (const float*)d_in[0];
    const int*   ei = (const int*)d_in[1];
    const int*   src = ei;
    const int*   dst = ei + N_EDGES;
    const float* W0 = (const float*)d_in[2];
    const float* b0 = (const float*)d_in[3];
    const float* W1 = (const float*)d_in[4];
    const float* b1 = (const float*)d_in[5];
    const float* W2 = (const float*)d_in[6];
    const float* b2 = (const float*)d_in[7];
    const float* Wr = (const float*)d_in[8];
    const float* br = (const float*)d_in[9];
    float* out = (float*)d_out;

    char* ws = (char*)d_ws;
    size_t off = 0;
    auto take = [&](size_t bytes) {
        char* p = ws + off;
        off += (bytes + 255) & ~(size_t)255;
        return p;
    };
    float* hA      = (float*)take((size_t)N_NODES * 128 * 4);
    float* hB      = (float*)take((size_t)N_NODES * 128 * 4);
    int*   counts  = (int*)take((size_t)N_NODES * 4);
    int*   rowstart= (int*)take((size_t)N_NODES * 4);
    int*   cursor  = (int*)take((size_t)N_NODES * 4);
    float* dis     = (float*)take((size_t)N_NODES * 4);
    int*   csr_src = (int*)take((size_t)N_EDGES * 4);
    int*   bsums   = (int*)take(1024 * 4);
    (void)ws_size; (void)in_sizes; (void)n_in; (void)out_size;

    hipMemsetAsync(counts, 0, (size_t)N_NODES * 4, stream);
    hipMemsetAsync(cursor, 0, (size_t)N_NODES * 4, stream);

    int nbE = (N_EDGES + 255) / 256;   // 6250
    int nbN = (N_NODES + 255) / 256;   // 391

    count_deg_kernel<<<nbE, 256, 0, stream>>>(dst, counts);
    compute_deg_kernel<<<nbN, 256, 0, stream>>>(counts, dis);
    scanA_kernel<<<nbN, 256, 0, stream>>>(counts, rowstart, bsums);
    scanB_kernel<<<1, 512, 0, stream>>>(bsums, nbN);
    scanC_kernel<<<nbN, 256, 0, stream>>>(rowstart, bsums);
    csr_fill_kernel<<<nbE, 256, 0, stream>>>(src, dst, rowstart, cursor, csr_src);

    const float* Wl[3] = {W0, W1, W2};
    const float* bl[3] = {b0, b1, b2};
    const float* hin = x;
    for (int l = 0; l < 3; l++) {
        // hB = (hin @ Wl) * dis  (pre-scaled by deg_inv_sqrt)
        gemm128_kernel<<<(N_NODES + 127) / 128, 256, 0, stream>>>(hin, Wl[l], dis, hB, N_NODES);
        aggregate_kernel<<<N_NODES / 4, 256, 0, stream>>>(hB, dis, rowstart, counts,
                                                          csr_src, bl[l], hA);
        hin = hA;
    }
    final_kernel<<<N_NODES / 16, 256, 0, stream>>>(hA, Wr, br, out);
}

// Round 5
// 677.035 us; speedup vs baseline: 4.1974x; 1.1994x over previous
//
#include <hip/hip_runtime.h>
#include <math.h>

#define N_NODES 100000
#define N_EDGES 1600000

// ---------------- bf16 helpers (manual, RNE) ----------------

static __device__ __forceinline__ unsigned short f2bf(float f) {
    unsigned int u = __float_as_uint(f);
    unsigned int r = (u + 0x7FFFu + ((u >> 16) & 1u)) >> 16;
    return (unsigned short)r;
}
static __device__ __forceinline__ float bf2f(unsigned short h) {
    return __uint_as_float(((unsigned int)h) << 16);
}

// ---------------- degree count ----------------

__global__ void count_deg_kernel(const int* __restrict__ dst, int* __restrict__ counts) {
    int e = blockIdx.x * 256 + threadIdx.x;
    if (e < N_EDGES) atomicAdd(&counts[dst[e]], 1);
}

__global__ void compute_deg_kernel(const int* __restrict__ counts,
                                   float* __restrict__ dis) {
    int i = blockIdx.x * 256 + threadIdx.x;
    if (i < N_NODES) {
        float deg = (float)(counts[i] + 1);   // self-loop
        dis[i] = rsqrtf(deg);
    }
}

// ---------------- prefix scan (rowstart) ----------------

__global__ void scanA_kernel(const int* __restrict__ counts, int* __restrict__ rowstart,
                             int* __restrict__ bsums) {
    __shared__ int s[256];
    int i = blockIdx.x * 256 + threadIdx.x;
    int v = (i < N_NODES) ? counts[i] : 0;
    s[threadIdx.x] = v;
    __syncthreads();
    for (int off = 1; off < 256; off <<= 1) {
        int t = 0;
        if (threadIdx.x >= off) t = s[threadIdx.x - off];
        __syncthreads();
        s[threadIdx.x] += t;
        __syncthreads();
    }
    if (i < N_NODES) rowstart[i] = s[threadIdx.x] - v;
    if (threadIdx.x == 255) bsums[blockIdx.x] = s[255];
}

__global__ void scanB_kernel(int* __restrict__ bsums, int nb) {
    __shared__ int s[512];
    int t = threadIdx.x;
    int v = (t < nb) ? bsums[t] : 0;
    s[t] = v;
    __syncthreads();
    for (int off = 1; off < 512; off <<= 1) {
        int u = 0;
        if (t >= off) u = s[t - off];
        __syncthreads();
        s[t] += u;
        __syncthreads();
    }
    if (t < nb) bsums[t] = s[t] - v;
}

__global__ void scanC_kernel(int* __restrict__ rowstart, const int* __restrict__ bsums) {
    int i = blockIdx.x * 256 + threadIdx.x;
    if (i < N_NODES) rowstart[i] += bsums[blockIdx.x];
}

// ---------------- CSR fill (direct per-node cursor; measured ~125us) ----------------

__global__ void csr_fill_kernel(const int* __restrict__ src, const int* __restrict__ dst,
                                const int* __restrict__ rowstart, int* __restrict__ cursor,
                                int* __restrict__ csr_src) {
    int e = blockIdx.x * 256 + threadIdx.x;
    if (e < N_EDGES) {
        int d = dst[e];
        int pos = rowstart[d] + atomicAdd(&cursor[d], 1);
        __builtin_nontemporal_store(src[e], &csr_src[pos]);
    }
}

// ---------------- GEMM: Yb(bf16)[N,128] = (X[N,128] @ W[128,128]) * scale[row] ----------------
// 128x128 tile, 256 threads, 8x8 micro-tile, A transposed in LDS. fp32 compute, bf16 store.

__global__ __launch_bounds__(256) void gemm128_kernel(const float* __restrict__ X,
                                                      const float* __restrict__ W,
                                                      const float* __restrict__ scale,
                                                      unsigned short* __restrict__ Yb,
                                                      int nrows) {
    __shared__ float As[16][132];   // [k][row]
    __shared__ float Bs[16][128];   // [k][col]
    int tid = threadIdx.x;
    int tx = tid & 15;    // col block: cols tx*8..+8
    int ty = tid >> 4;    // row block: rows ty*8..+8
    int rowBase = blockIdx.x * 128;

    float acc[8][8];
#pragma unroll
    for (int i = 0; i < 8; i++)
#pragma unroll
        for (int j = 0; j < 8; j++) acc[i][j] = 0.f;

    int a_r  = tid >> 1;          // 0..127
    int a_k4 = (tid & 1) * 8;     // 0 or 8

    for (int kb = 0; kb < 128; kb += 16) {
        {
            int grow = rowBase + a_r;
            float4 v0 = make_float4(0.f,0.f,0.f,0.f), v1 = v0;
            if (grow < nrows) {
                v0 = *(const float4*)&X[(size_t)grow * 128 + kb + a_k4];
                v1 = *(const float4*)&X[(size_t)grow * 128 + kb + a_k4 + 4];
            }
            As[a_k4 + 0][a_r] = v0.x; As[a_k4 + 1][a_r] = v0.y;
            As[a_k4 + 2][a_r] = v0.z; As[a_k4 + 3][a_r] = v0.w;
            As[a_k4 + 4][a_r] = v1.x; As[a_k4 + 5][a_r] = v1.y;
            As[a_k4 + 6][a_r] = v1.z; As[a_k4 + 7][a_r] = v1.w;
        }
        {
            int f0 = tid, f1 = tid + 256;
            *(float4*)&Bs[f0 >> 5][(f0 & 31) * 4] =
                *(const float4*)&W[(size_t)(kb + (f0 >> 5)) * 128 + (f0 & 31) * 4];
            *(float4*)&Bs[f1 >> 5][(f1 & 31) * 4] =
                *(const float4*)&W[(size_t)(kb + (f1 >> 5)) * 128 + (f1 & 31) * 4];
        }
        __syncthreads();
#pragma unroll
        for (int kk = 0; kk < 16; kk++) {
            float4 a0 = *(const float4*)&As[kk][ty * 8];
            float4 a1 = *(const float4*)&As[kk][ty * 8 + 4];
            float4 b0 = *(const float4*)&Bs[kk][tx * 8];
            float4 b1 = *(const float4*)&Bs[kk][tx * 8 + 4];
            float a[8] = {a0.x,a0.y,a0.z,a0.w,a1.x,a1.y,a1.z,a1.w};
            float b[8] = {b0.x,b0.y,b0.z,b0.w,b1.x,b1.y,b1.z,b1.w};
#pragma unroll
            for (int i = 0; i < 8; i++)
#pragma unroll
                for (int j = 0; j < 8; j++) acc[i][j] = fmaf(a[i], b[j], acc[i][j]);
        }
        __syncthreads();
    }
    // epilogue: rows ty*8..+8, cols tx*8..+8, pre-scale by dis, pack to bf16 (16B store)
#pragma unroll
    for (int i = 0; i < 8; i++) {
        int grow = rowBase + ty * 8 + i;
        if (grow < nrows) {
            float s = scale[grow];
            unsigned int p0 = (unsigned int)f2bf(acc[i][0]*s) | ((unsigned int)f2bf(acc[i][1]*s) << 16);
            unsigned int p1 = (unsigned int)f2bf(acc[i][2]*s) | ((unsigned int)f2bf(acc[i][3]*s) << 16);
            unsigned int p2 = (unsigned int)f2bf(acc[i][4]*s) | ((unsigned int)f2bf(acc[i][5]*s) << 16);
            unsigned int p3 = (unsigned int)f2bf(acc[i][6]*s) | ((unsigned int)f2bf(acc[i][7]*s) << 16);
            uint4 pk = make_uint4(p0, p1, p2, p3);
            *(uint4*)&Yb[(size_t)grow * 128 + tx * 8] = pk;
        }
    }
}

// ---------------- Aggregation over bf16 rows ----------------
// Hs (bf16) = h*dis pre-scaled. out[i] = relu(b + dis[i]*(Hs[i] + sum_src Hs[src]))
// One wave per node; lane owns 2 bf16 channels -> each gather = one 256B coalesced row.

__global__ __launch_bounds__(256) void aggregate_kernel(const unsigned short* __restrict__ Hs,
                                                        const float* __restrict__ dis,
                                                        const int* __restrict__ rowstart,
                                                        const int* __restrict__ counts,
                                                        const int* __restrict__ csr_src,
                                                        const float* __restrict__ bias,
                                                        float* __restrict__ Out) {
    int node = blockIdx.x * 4 + (threadIdx.x >> 6);
    node = __builtin_amdgcn_readfirstlane(node);   // wave-uniform -> scalar loads
    int lane = threadIdx.x & 63;
    if (node >= N_NODES) return;
    int c0 = lane * 2;

    unsigned int ow = *(const unsigned int*)&Hs[(size_t)node * 128 + c0];
    float accx = bf2f((unsigned short)(ow & 0xffffu));
    float accy = bf2f((unsigned short)(ow >> 16));

    int start = rowstart[node];
    int cnt   = counts[node];
    int end = start + cnt;
    int j = start;

    // 8 independent 256B row-gathers in flight
    for (; j + 7 < end; j += 8) {
        int s0 = __builtin_nontemporal_load(&csr_src[j]);
        int s1 = __builtin_nontemporal_load(&csr_src[j + 1]);
        int s2 = __builtin_nontemporal_load(&csr_src[j + 2]);
        int s3 = __builtin_nontemporal_load(&csr_src[j + 3]);
        int s4 = __builtin_nontemporal_load(&csr_src[j + 4]);
        int s5 = __builtin_nontemporal_load(&csr_src[j + 5]);
        int s6 = __builtin_nontemporal_load(&csr_src[j + 6]);
        int s7 = __builtin_nontemporal_load(&csr_src[j + 7]);
        unsigned int w0 = *(const unsigned int*)&Hs[(size_t)s0 * 128 + c0];
        unsigned int w1 = *(const unsigned int*)&Hs[(size_t)s1 * 128 + c0];
        unsigned int w2 = *(const unsigned int*)&Hs[(size_t)s2 * 128 + c0];
        unsigned int w3 = *(const unsigned int*)&Hs[(size_t)s3 * 128 + c0];
        unsigned int w4 = *(const unsigned int*)&Hs[(size_t)s4 * 128 + c0];
        unsigned int w5 = *(const unsigned int*)&Hs[(size_t)s5 * 128 + c0];
        unsigned int w6 = *(const unsigned int*)&Hs[(size_t)s6 * 128 + c0];
        unsigned int w7 = *(const unsigned int*)&Hs[(size_t)s7 * 128 + c0];
        accx += ((bf2f((unsigned short)(w0 & 0xffffu)) + bf2f((unsigned short)(w1 & 0xffffu)))
               + (bf2f((unsigned short)(w2 & 0xffffu)) + bf2f((unsigned short)(w3 & 0xffffu))))
              + ((bf2f((unsigned short)(w4 & 0xffffu)) + bf2f((unsigned short)(w5 & 0xffffu)))
               + (bf2f((unsigned short)(w6 & 0xffffu)) + bf2f((unsigned short)(w7 & 0xffffu))));
        accy += ((bf2f((unsigned short)(w0 >> 16)) + bf2f((unsigned short)(w1 >> 16)))
               + (bf2f((unsigned short)(w2 >> 16)) + bf2f((unsigned short)(w3 >> 16))))
              + ((bf2f((unsigned short)(w4 >> 16)) + bf2f((unsigned short)(w5 >> 16)))
               + (bf2f((unsigned short)(w6 >> 16)) + bf2f((unsigned short)(w7 >> 16))));
    }
    for (; j + 1 < end; j += 2) {
        int s0 = __builtin_nontemporal_load(&csr_src[j]);
        int s1 = __builtin_nontemporal_load(&csr_src[j + 1]);
        unsigned int w0 = *(const unsigned int*)&Hs[(size_t)s0 * 128 + c0];
        unsigned int w1 = *(const unsigned int*)&Hs[(size_t)s1 * 128 + c0];
        accx += bf2f((unsigned short)(w0 & 0xffffu)) + bf2f((unsigned short)(w1 & 0xffffu));
        accy += bf2f((unsigned short)(w0 >> 16)) + bf2f((unsigned short)(w1 >> 16));
    }
    if (j < end) {
        int s0 = __builtin_nontemporal_load(&csr_src[j]);
        unsigned int w0 = *(const unsigned int*)&Hs[(size_t)s0 * 128 + c0];
        accx += bf2f((unsigned short)(w0 & 0xffffu));
        accy += bf2f((unsigned short)(w0 >> 16));
    }

    float dsi = dis[node];
    float2 bb = *(const float2*)&bias[c0];
    float2 r;
    r.x = fmaxf(fmaf(accx, dsi, bb.x), 0.f);
    r.y = fmaxf(fmaf(accy, dsi, bb.y), 0.f);
    unsigned long long bits;
    __builtin_memcpy(&bits, &r, 8);
    __builtin_nontemporal_store(bits, (unsigned long long*)&Out[(size_t)node * 128 + c0]);
}

// ---------------- Final: out = sigmoid(H @ Wr + br)*0.8 + 0.1 ----------------

__global__ __launch_bounds__(256) void final_kernel(const float* __restrict__ H,
                                                    const float* __restrict__ Wr,
                                                    const float* __restrict__ br,
                                                    float* __restrict__ out) {
    __shared__ float hs[16][132];
    __shared__ float ws[128][16];
    int tid = threadIdx.x;
    int rowBase = blockIdx.x * 16;
    {
        int k  = tid & 127;
        int r0 = tid >> 7;
#pragma unroll
        for (int rr = 0; rr < 8; rr++) {
            int r = r0 + rr * 2;
            int grow = rowBase + r;
            hs[r][k] = (grow < N_NODES) ? H[(size_t)grow * 128 + k] : 0.f;
        }
#pragma unroll
        for (int q = 0; q < 8; q++) {
            int idx = q * 256 + tid;
            ws[idx >> 4][idx & 15] = Wr[idx];
        }
    }
    __syncthreads();
    int row = tid >> 4;
    int c   = tid & 15;
    float acc = br[c];
#pragma unroll
    for (int k = 0; k < 128; k++)
        acc = fmaf(hs[row][k], ws[k][c], acc);
    int grow = rowBase + row;
    if (grow < N_NODES) {
        float sg = 1.f / (1.f + expf(-acc));
        out[(size_t)grow * 16 + c] = 0.8f * sg + 0.1f;
    }
}

// ---------------- Launch ----------------

extern "C" void kernel_launch(void* const* d_in, const int* in_sizes, int n_in,
                              void* d_out, int out_size, void* d_ws, size_t ws_size,
                              hipStream_t stream) {
    const float* x  = (const float*)d_in[0];
    const int*   ei = (const int*)d_in[1];
    const int*   src = ei;
    const int*   dst = ei + N_EDGES;
    const float* W0 = (const float*)d_in[2];
    const float* b0 = (const float*)d_in[3];
    const float* W1 = (const float*)d_in[4];
    const float* b1 = (const float*)d_in[5];
    const float* W2 = (const float*)d_in[6];
    const float* b2 = (const float*)d_in[7];
    const float* Wr = (const float*)d_in[8];
    const float* br = (const float*)d_in[9];
    float* out = (float*)d_out;

    char* ws = (char*)d_ws;
    size_t off = 0;
    auto take = [&](size_t bytes) {
        char* p = ws + off;
        off += (bytes + 255) & ~(size_t)255;
        return p;
    };
    float*          hA      = (float*)take((size_t)N_NODES * 128 * 4);          // agg out, fp32
    unsigned short* hBs     = (unsigned short*)take((size_t)N_NODES * 128 * 2); // gemm out, bf16
    int*            counts  = (int*)take((size_t)N_NODES * 4);
    int*            rowstart= (int*)take((size_t)N_NODES * 4);
    int*            cursor  = (int*)take((size_t)N_NODES * 4);
    float*          dis     = (float*)take((size_t)N_NODES * 4);
    int*            csr_src = (int*)take((size_t)N_EDGES * 4);
    int*            bsums   = (int*)take(1024 * 4);
    (void)ws_size; (void)in_sizes; (void)n_in; (void)out_size;

    hipMemsetAsync(counts, 0, (size_t)N_NODES * 4, stream);
    hipMemsetAsync(cursor, 0, (size_t)N_NODES * 4, stream);

    int nbE = (N_EDGES + 255) / 256;   // 6250
    int nbN = (N_NODES + 255) / 256;   // 391

    count_deg_kernel<<<nbE, 256, 0, stream>>>(dst, counts);
    compute_deg_kernel<<<nbN, 256, 0, stream>>>(counts, dis);
    scanA_kernel<<<nbN, 256, 0, stream>>>(counts, rowstart, bsums);
    scanB_kernel<<<1, 512, 0, stream>>>(bsums, nbN);
    scanC_kernel<<<nbN, 256, 0, stream>>>(rowstart, bsums);
    csr_fill_kernel<<<nbE, 256, 0, stream>>>(src, dst, rowstart, cursor, csr_src);

    const float* Wl[3] = {W0, W1, W2};
    const float* bl[3] = {b0, b1, b2};
    const float* hin = x;
    for (int l = 0; l < 3; l++) {
        // hBs = bf16( (hin @ Wl) * dis )
        gemm128_kernel<<<(N_NODES + 127) / 128, 256, 0, stream>>>(hin, Wl[l], dis, hBs, N_NODES);
        aggregate_kernel<<<N_NODES / 4, 256, 0, stream>>>(hBs, dis, rowstart, counts,
                                                          csr_src, bl[l], hA);
        hin = hA;
    }
    final_kernel<<<N_NODES / 16, 256, 0, stream>>>(hA, Wr, br, out);
}

// Round 7
// 543.675 us; speedup vs baseline: 5.2269x; 1.2453x over previous
//
#include <hip/hip_runtime.h>
#include <math.h>

#define N_NODES 100000
#define N_EDGES 1600000
#define NBUCKET 782            // ceil(N_NODES/128), 128 nodes per bucket
#define EB      256            // edge-blocks for hist/scatter
#define EPB     6250           // edges per block (EB*EPB == N_EDGES)

// ---------------- bf16 helpers (manual, RNE) ----------------

static __device__ __forceinline__ unsigned short f2bf(float f) {
    unsigned int u = __float_as_uint(f);
    unsigned int r = (u + 0x7FFFu + ((u >> 16) & 1u)) >> 16;
    return (unsigned short)r;
}
static __device__ __forceinline__ float bf2f(unsigned short h) {
    return __uint_as_float(((unsigned int)h) << 16);
}

// ---------------- CSR build: contention-free counting sort ----------------
// Record pack: src in bits 0..16, (dst&127) in bits 20..26.

__global__ __launch_bounds__(256) void hist_kernel(const int* __restrict__ dst,
                                                   int* __restrict__ hist /*[EB][NBUCKET]*/) {
    __shared__ int h[NBUCKET];
    int tid = threadIdx.x;
    for (int b = tid; b < NBUCKET; b += 256) h[b] = 0;
    __syncthreads();
    int base = blockIdx.x * EPB;
    for (int i = tid; i < EPB; i += 256)
        atomicAdd(&h[dst[base + i] >> 7], 1);
    __syncthreads();
    int* hrow = hist + (size_t)blockIdx.x * NBUCKET;
    for (int b = tid; b < NBUCKET; b += 256) hrow[b] = h[b];
}

// Per bucket: exclusive scan of the 256 per-block counts -> blkoffT[bucket][block];
// bucket total -> btotal[bucket].
__global__ __launch_bounds__(256) void scan_hist_kernel(const int* __restrict__ hist,
                                                        int* __restrict__ blkoffT,
                                                        int* __restrict__ btotal) {
    __shared__ int s[256];
    int b = blockIdx.x;
    int k = threadIdx.x;
    int v = hist[(size_t)k * NBUCKET + b];
    s[k] = v;
    __syncthreads();
    for (int off = 1; off < 256; off <<= 1) {
        int t = 0;
        if (k >= off) t = s[k - off];
        __syncthreads();
        s[k] += t;
        __syncthreads();
    }
    blkoffT[(size_t)b * 256 + k] = s[k] - v;   // exclusive, sequential 1KB row write
    if (k == 255) btotal[b] = s[255];
}

// Exclusive scan of 782 bucket totals -> bucket_start[0..782] (incl. total at [782]).
__global__ __launch_bounds__(256) void bucket_scan_kernel(const int* __restrict__ btotal,
                                                          int* __restrict__ bucket_start) {
    __shared__ int cs[256];
    int tid = threadIdx.x;
    int base = tid * 4;
    int v[4];
    int sum = 0;
#pragma unroll
    for (int q = 0; q < 4; q++) {
        int idx = base + q;
        v[q] = (idx < NBUCKET) ? btotal[idx] : 0;
        sum += v[q];
    }
    cs[tid] = sum;
    __syncthreads();
    for (int off = 1; off < 256; off <<= 1) {
        int t = 0;
        if (tid >= off) t = cs[tid - off];
        __syncthreads();
        cs[tid] += t;
        __syncthreads();
    }
    int run = cs[tid] - sum;   // exclusive prefix of this thread's chunk
#pragma unroll
    for (int q = 0; q < 4; q++) {
        int idx = base + q;
        if (idx < NBUCKET + 1) bucket_start[idx] = run;
        run += v[q];
    }
}

// Scatter packed records into bucket-major order. Per-(block,bucket) regions are
// contiguous (~8 edges * 4B) -> cache lines fill; no global atomics.
__global__ __launch_bounds__(256) void scatter_kernel(const int* __restrict__ src,
                                                      const int* __restrict__ dst,
                                                      const int* __restrict__ blkoffT,
                                                      const int* __restrict__ bucket_start,
                                                      int* __restrict__ pairs) {
    __shared__ int cur[NBUCKET];
    int tid = threadIdx.x;
    for (int b = tid; b < NBUCKET; b += 256)
        cur[b] = bucket_start[b] + blkoffT[(size_t)b * 256 + blockIdx.x];
    __syncthreads();
    int base = blockIdx.x * EPB;
    for (int i = tid; i < EPB; i += 256) {
        int d = dst[base + i];
        int s = src[base + i];
        int pos = atomicAdd(&cur[d >> 7], 1);
        pairs[pos] = s | ((d & 127) << 20);
    }
}

// One block per bucket: per-node counts + scan (-> rowstart/counts/dis), then
// exact CSR fill inside the bucket's L2-hot ~8KB region.
__global__ __launch_bounds__(256) void build_csr_kernel(const int* __restrict__ pairs,
                                                        const int* __restrict__ bucket_start,
                                                        int* __restrict__ rowstart,
                                                        int* __restrict__ counts,
                                                        float* __restrict__ dis,
                                                        int* __restrict__ csr_src) {
    __shared__ int lcnt[128];
    __shared__ int lsc[128];
    __shared__ int lcur[128];
    int tid = threadIdx.x;
    int b = blockIdx.x;
    int node_base = b * 128;
    if (tid < 128) lcnt[tid] = 0;
    __syncthreads();
    int rs = bucket_start[b];
    int re = bucket_start[b + 1];
    for (int e = rs + tid; e < re; e += 256)
        atomicAdd(&lcnt[pairs[e] >> 20], 1);
    __syncthreads();
    if (tid < 128) lsc[tid] = lcnt[tid];
    __syncthreads();
    for (int off = 1; off < 128; off <<= 1) {
        int t = 0;
        if (tid < 128 && tid >= off) t = lsc[tid - off];
        __syncthreads();
        if (tid < 128) lsc[tid] += t;
        __syncthreads();
    }
    if (tid < 128) {
        int node = node_base + tid;
        if (node < N_NODES) {
            int startg = rs + lsc[tid] - lcnt[tid];
            rowstart[node] = startg;
            counts[node]   = lcnt[tid];
            dis[node]      = rsqrtf((float)(lcnt[tid] + 1));
            lcur[tid]      = startg;
        }
    }
    __syncthreads();
    for (int e = rs + tid; e < re; e += 256) {
        int v = pairs[e];
        int pos = atomicAdd(&lcur[v >> 20], 1);
        csr_src[pos] = v & 0xFFFFF;
    }
}

// ---------------- GEMM: Yb(bf16)[N,128] = (X[N,128] @ W[128,128]) * scale[row] ----------------
// 128x128 tile, 256 threads, 8x8 micro-tile, A transposed in LDS. fp32 compute, bf16 store.

__global__ __launch_bounds__(256) void gemm128_kernel(const float* __restrict__ X,
                                                      const float* __restrict__ W,
                                                      const float* __restrict__ scale,
                                                      unsigned short* __restrict__ Yb,
                                                      int nrows) {
    __shared__ float As[16][132];   // [k][row]
    __shared__ float Bs[16][128];   // [k][col]
    int tid = threadIdx.x;
    int tx = tid & 15;    // col block: cols tx*8..+8
    int ty = tid >> 4;    // row block: rows ty*8..+8
    int rowBase = blockIdx.x * 128;

    float acc[8][8];
#pragma unroll
    for (int i = 0; i < 8; i++)
#pragma unroll
        for (int j = 0; j < 8; j++) acc[i][j] = 0.f;

    int a_r  = tid >> 1;          // 0..127
    int a_k4 = (tid & 1) * 8;     // 0 or 8

    for (int kb = 0; kb < 128; kb += 16) {
        {
            int grow = rowBase + a_r;
            float4 v0 = make_float4(0.f,0.f,0.f,0.f), v1 = v0;
            if (grow < nrows) {
                v0 = *(const float4*)&X[(size_t)grow * 128 + kb + a_k4];
                v1 = *(const float4*)&X[(size_t)grow * 128 + kb + a_k4 + 4];
            }
            As[a_k4 + 0][a_r] = v0.x; As[a_k4 + 1][a_r] = v0.y;
            As[a_k4 + 2][a_r] = v0.z; As[a_k4 + 3][a_r] = v0.w;
            As[a_k4 + 4][a_r] = v1.x; As[a_k4 + 5][a_r] = v1.y;
            As[a_k4 + 6][a_r] = v1.z; As[a_k4 + 7][a_r] = v1.w;
        }
        {
            int f0 = tid, f1 = tid + 256;
            *(float4*)&Bs[f0 >> 5][(f0 & 31) * 4] =
                *(const float4*)&W[(size_t)(kb + (f0 >> 5)) * 128 + (f0 & 31) * 4];
            *(float4*)&Bs[f1 >> 5][(f1 & 31) * 4] =
                *(const float4*)&W[(size_t)(kb + (f1 >> 5)) * 128 + (f1 & 31) * 4];
        }
        __syncthreads();
#pragma unroll
        for (int kk = 0; kk < 16; kk++) {
            float4 a0 = *(const float4*)&As[kk][ty * 8];
            float4 a1 = *(const float4*)&As[kk][ty * 8 + 4];
            float4 b0 = *(const float4*)&Bs[kk][tx * 8];
            float4 b1 = *(const float4*)&Bs[kk][tx * 8 + 4];
            float a[8] = {a0.x,a0.y,a0.z,a0.w,a1.x,a1.y,a1.z,a1.w};
            float b[8] = {b0.x,b0.y,b0.z,b0.w,b1.x,b1.y,b1.z,b1.w};
#pragma unroll
            for (int i = 0; i < 8; i++)
#pragma unroll
                for (int j = 0; j < 8; j++) acc[i][j] = fmaf(a[i], b[j], acc[i][j]);
        }
        __syncthreads();
    }
#pragma unroll
    for (int i = 0; i < 8; i++) {
        int grow = rowBase + ty * 8 + i;
        if (grow < nrows) {
            float s = scale[grow];
            unsigned int p0 = (unsigned int)f2bf(acc[i][0]*s) | ((unsigned int)f2bf(acc[i][1]*s) << 16);
            unsigned int p1 = (unsigned int)f2bf(acc[i][2]*s) | ((unsigned int)f2bf(acc[i][3]*s) << 16);
            unsigned int p2 = (unsigned int)f2bf(acc[i][4]*s) | ((unsigned int)f2bf(acc[i][5]*s) << 16);
            unsigned int p3 = (unsigned int)f2bf(acc[i][6]*s) | ((unsigned int)f2bf(acc[i][7]*s) << 16);
            uint4 pk = make_uint4(p0, p1, p2, p3);
            *(uint4*)&Yb[(size_t)grow * 128 + tx * 8] = pk;
        }
    }
}

// ---------------- Aggregation over bf16 rows ----------------
// Hs (bf16) = h*dis pre-scaled. out[i] = relu(b + dis[i]*(Hs[i] + sum_src Hs[src]))
// One wave per node; lane owns 2 bf16 channels -> each gather = one 256B coalesced row.

__global__ __launch_bounds__(256) void aggregate_kernel(const unsigned short* __restrict__ Hs,
                                                        const float* __restrict__ dis,
                                                        const int* __restrict__ rowstart,
                                                        const int* __restrict__ counts,
                                                        const int* __restrict__ csr_src,
                                                        const float* __restrict__ bias,
                                                        float* __restrict__ Out) {
    int node = blockIdx.x * 4 + (threadIdx.x >> 6);
    node = __builtin_amdgcn_readfirstlane(node);   // wave-uniform -> scalar loads
    int lane = threadIdx.x & 63;
    if (node >= N_NODES) return;
    int c0 = lane * 2;

    unsigned int ow = *(const unsigned int*)&Hs[(size_t)node * 128 + c0];
    float accx = bf2f((unsigned short)(ow & 0xffffu));
    float accy = bf2f((unsigned short)(ow >> 16));

    int start = rowstart[node];
    int cnt   = counts[node];
    int end = start + cnt;
    int j = start;

    for (; j + 7 < end; j += 8) {
        int s0 = __builtin_nontemporal_load(&csr_src[j]);
        int s1 = __builtin_nontemporal_load(&csr_src[j + 1]);
        int s2 = __builtin_nontemporal_load(&csr_src[j + 2]);
        int s3 = __builtin_nontemporal_load(&csr_src[j + 3]);
        int s4 = __builtin_nontemporal_load(&csr_src[j + 4]);
        int s5 = __builtin_nontemporal_load(&csr_src[j + 5]);
        int s6 = __builtin_nontemporal_load(&csr_src[j + 6]);
        int s7 = __builtin_nontemporal_load(&csr_src[j + 7]);
        unsigned int w0 = *(const unsigned int*)&Hs[(size_t)s0 * 128 + c0];
        unsigned int w1 = *(const unsigned int*)&Hs[(size_t)s1 * 128 + c0];
        unsigned int w2 = *(const unsigned int*)&Hs[(size_t)s2 * 128 + c0];
        unsigned int w3 = *(const unsigned int*)&Hs[(size_t)s3 * 128 + c0];
        unsigned int w4 = *(const unsigned int*)&Hs[(size_t)s4 * 128 + c0];
        unsigned int w5 = *(const unsigned int*)&Hs[(size_t)s5 * 128 + c0];
        unsigned int w6 = *(const unsigned int*)&Hs[(size_t)s6 * 128 + c0];
        unsigned int w7 = *(const unsigned int*)&Hs[(size_t)s7 * 128 + c0];
        accx += ((bf2f((unsigned short)(w0 & 0xffffu)) + bf2f((unsigned short)(w1 & 0xffffu)))
               + (bf2f((unsigned short)(w2 & 0xffffu)) + bf2f((unsigned short)(w3 & 0xffffu))))
              + ((bf2f((unsigned short)(w4 & 0xffffu)) + bf2f((unsigned short)(w5 & 0xffffu)))
               + (bf2f((unsigned short)(w6 & 0xffffu)) + bf2f((unsigned short)(w7 & 0xffffu))));
        accy += ((bf2f((unsigned short)(w0 >> 16)) + bf2f((unsigned short)(w1 >> 16)))
               + (bf2f((unsigned short)(w2 >> 16)) + bf2f((unsigned short)(w3 >> 16))))
              + ((bf2f((unsigned short)(w4 >> 16)) + bf2f((unsigned short)(w5 >> 16)))
               + (bf2f((unsigned short)(w6 >> 16)) + bf2f((unsigned short)(w7 >> 16))));
    }
    for (; j + 1 < end; j += 2) {
        int s0 = __builtin_nontemporal_load(&csr_src[j]);
        int s1 = __builtin_nontemporal_load(&csr_src[j + 1]);
        unsigned int w0 = *(const unsigned int*)&Hs[(size_t)s0 * 128 + c0];
        unsigned int w1 = *(const unsigned int*)&Hs[(size_t)s1 * 128 + c0];
        accx += bf2f((unsigned short)(w0 & 0xffffu)) + bf2f((unsigned short)(w1 & 0xffffu));
        accy += bf2f((unsigned short)(w0 >> 16)) + bf2f((unsigned short)(w1 >> 16));
    }
    if (j < end) {
        int s0 = __builtin_nontemporal_load(&csr_src[j]);
        unsigned int w0 = *(const unsigned int*)&Hs[(size_t)s0 * 128 + c0];
        accx += bf2f((unsigned short)(w0 & 0xffffu));
        accy += bf2f((unsigned short)(w0 >> 16));
    }

    float dsi = dis[node];
    float2 bb = *(const float2*)&bias[c0];
    float2 r;
    r.x = fmaxf(fmaf(accx, dsi, bb.x), 0.f);
    r.y = fmaxf(fmaf(accy, dsi, bb.y), 0.f);
    unsigned long long bits;
    __builtin_memcpy(&bits, &r, 8);
    __builtin_nontemporal_store(bits, (unsigned long long*)&Out[(size_t)node * 128 + c0]);
}

// ---------------- Final: out = sigmoid(H @ Wr + br)*0.8 + 0.1 ----------------

__global__ __launch_bounds__(256) void final_kernel(const float* __restrict__ H,
                                                    const float* __restrict__ Wr,
                                                    const float* __restrict__ br,
                                                    float* __restrict__ out) {
    __shared__ float hs[16][132];
    __shared__ float ws[128][16];
    int tid = threadIdx.x;
    int rowBase = blockIdx.x * 16;
    {
        int k  = tid & 127;
        int r0 = tid >> 7;
#pragma unroll
        for (int rr = 0; rr < 8; rr++) {
            int r = r0 + rr * 2;
            int grow = rowBase + r;
            hs[r][k] = (grow < N_NODES) ? H[(size_t)grow * 128 + k] : 0.f;
        }
#pragma unroll
        for (int q = 0; q < 8; q++) {
            int idx = q * 256 + tid;
            ws[idx >> 4][idx & 15] = Wr[idx];
        }
    }
    __syncthreads();
    int row = tid >> 4;
    int c   = tid & 15;
    float acc = br[c];
#pragma unroll
    for (int k = 0; k < 128; k++)
        acc = fmaf(hs[row][k], ws[k][c], acc);
    int grow = rowBase + row;
    if (grow < N_NODES) {
        float sg = 1.f / (1.f + expf(-acc));
        out[(size_t)grow * 16 + c] = 0.8f * sg + 0.1f;
    }
}

// ---------------- Launch ----------------

extern "C" void kernel_launch(void* const* d_in, const int* in_sizes, int n_in,
                              void* d_out, int out_size, void* d_ws, size_t ws_size,
                              hipStream_t stream) {
    const float* x  = (const float*)d_in[0];
    const int*   ei = (const int*)d_in[1];
    const int*   src = ei;
    const int*   dst = ei + N_EDGES;
    const float* W0 = (const float*)d_in[2];
    const float* b0 = (const float*)d_in[3];
    const float* W1 = (const float*)d_in[4];
    const float* b1 = (const float*)d_in[5];
    const float* W2 = (const float*)d_in[6];
    const float* b2 = (const float*)d_in[7];
    const float* Wr = (const float*)d_in[8];
    const float* br = (const float*)d_in[9];
    float* out = (float*)d_out;

    char* ws = (char*)d_ws;
    size_t off = 0;
    auto take = [&](size_t bytes) {
        char* p = ws + off;
        off += (bytes + 255) & ~(size_t)255;
        return p;
    };
    float*          hA       = (float*)take((size_t)N_NODES * 128 * 4);          // agg out, fp32
    unsigned short* hBs      = (unsigned short*)take((size_t)N_NODES * 128 * 2); // gemm out, bf16
    int*            counts   = (int*)take((size_t)N_NODES * 4);
    int*            rowstart = (int*)take((size_t)N_NODES * 4);
    float*          dis      = (float*)take((size_t)N_NODES * 4);
    int*            csr_src  = (int*)take((size_t)N_EDGES * 4);
    int*            pairs    = (int*)take((size_t)N_EDGES * 4);
    int*            hist     = (int*)take((size_t)EB * NBUCKET * 4);     // [EB][NBUCKET]
    int*            blkoffT  = (int*)take((size_t)NBUCKET * EB * 4);     // [NBUCKET][EB]
    int*            btotal   = (int*)take(1024 * 4);
    int*            bstart   = (int*)take(1024 * 4);
    (void)ws_size; (void)in_sizes; (void)n_in; (void)out_size;

    // CSR build: no global atomics, line-local scatters.
    hist_kernel<<<EB, 256, 0, stream>>>(dst, hist);
    scan_hist_kernel<<<NBUCKET, 256, 0, stream>>>(hist, blkoffT, btotal);
    bucket_scan_kernel<<<1, 256, 0, stream>>>(btotal, bstart);
    scatter_kernel<<<EB, 256, 0, stream>>>(src, dst, blkoffT, bstart, pairs);
    build_csr_kernel<<<NBUCKET, 256, 0, stream>>>(pairs, bstart, rowstart, counts, dis, csr_src);

    const float* Wl[3] = {W0, W1, W2};
    const float* bl[3] = {b0, b1, b2};
    const float* hin = x;
    for (int l = 0; l < 3; l++) {
        // hBs = bf16( (hin @ Wl) * dis )
        gemm128_kernel<<<(N_NODES + 127) / 128, 256, 0, stream>>>(hin, Wl[l], dis, hBs, N_NODES);
        aggregate_kernel<<<N_NODES / 4, 256, 0, stream>>>(hBs, dis, rowstart, counts,
                                                          csr_src, bl[l], hA);
        hin = hA;
    }
    final_kernel<<<N_NODES / 16, 256, 0, stream>>>(hA, Wr, br, out);
}

// Round 8
// 478.469 us; speedup vs baseline: 5.9393x; 1.1363x over previous
//
#include <hip/hip_runtime.h>
#include <math.h>

#define N_NODES 100000
#define N_EDGES 1600000
#define NBUCKET 782            // ceil(N_NODES/128), 128 nodes per bucket
#define EB      256            // edge-blocks for hist/scatter
#define EPB     6250           // edges per block (EB*EPB == N_EDGES)

typedef __attribute__((ext_vector_type(8))) __bf16 bf16x8;
typedef __attribute__((ext_vector_type(4))) float  f32x4;

// ---------------- bf16 helpers (manual, RNE) ----------------

static __device__ __forceinline__ unsigned short f2bf(float f) {
    unsigned int u = __float_as_uint(f);
    unsigned int r = (u + 0x7FFFu + ((u >> 16) & 1u)) >> 16;
    return (unsigned short)r;
}
static __device__ __forceinline__ float bf2f(unsigned short h) {
    return __uint_as_float(((unsigned int)h) << 16);
}

// ---------------- input conversions ----------------

__global__ __launch_bounds__(256) void xconv_kernel(const float* __restrict__ X,
                                                    unsigned short* __restrict__ Xb) {
    int i = (blockIdx.x * 256 + threadIdx.x) * 4;   // grid sized exactly
    float4 v = *(const float4*)&X[i];
    unsigned int p0 = (unsigned int)f2bf(v.x) | ((unsigned int)f2bf(v.y) << 16);
    unsigned int p1 = (unsigned int)f2bf(v.z) | ((unsigned int)f2bf(v.w) << 16);
    *(uint2*)&Xb[i] = make_uint2(p0, p1);
}

// Wt[n][k] = bf16(W[k][n])
__global__ void wconv_kernel(const float* __restrict__ W, unsigned short* __restrict__ Wt) {
    int n = blockIdx.x;
    int k = threadIdx.x;
    Wt[n * 128 + k] = f2bf(W[k * 128 + n]);
}

// ---------------- CSR build: contention-free counting sort ----------------
// Record pack: src in bits 0..16, (dst&127) in bits 20..26.

__global__ __launch_bounds__(256) void hist_kernel(const int* __restrict__ dst,
                                                   int* __restrict__ hist /*[EB][NBUCKET]*/) {
    __shared__ int h[NBUCKET];
    int tid = threadIdx.x;
    for (int b = tid; b < NBUCKET; b += 256) h[b] = 0;
    __syncthreads();
    int base = blockIdx.x * EPB;
    for (int i = tid; i < EPB; i += 256)
        atomicAdd(&h[dst[base + i] >> 7], 1);
    __syncthreads();
    int* hrow = hist + (size_t)blockIdx.x * NBUCKET;
    for (int b = tid; b < NBUCKET; b += 256) hrow[b] = h[b];
}

__global__ __launch_bounds__(256) void scan_hist_kernel(const int* __restrict__ hist,
                                                        int* __restrict__ blkoffT,
                                                        int* __restrict__ btotal) {
    __shared__ int s[256];
    int b = blockIdx.x;
    int k = threadIdx.x;
    int v = hist[(size_t)k * NBUCKET + b];
    s[k] = v;
    __syncthreads();
    for (int off = 1; off < 256; off <<= 1) {
        int t = 0;
        if (k >= off) t = s[k - off];
        __syncthreads();
        s[k] += t;
        __syncthreads();
    }
    blkoffT[(size_t)b * 256 + k] = s[k] - v;
    if (k == 255) btotal[b] = s[255];
}

__global__ __launch_bounds__(256) void bucket_scan_kernel(const int* __restrict__ btotal,
                                                          int* __restrict__ bucket_start) {
    __shared__ int cs[256];
    int tid = threadIdx.x;
    int base = tid * 4;
    int v[4];
    int sum = 0;
#pragma unroll
    for (int q = 0; q < 4; q++) {
        int idx = base + q;
        v[q] = (idx < NBUCKET) ? btotal[idx] : 0;
        sum += v[q];
    }
    cs[tid] = sum;
    __syncthreads();
    for (int off = 1; off < 256; off <<= 1) {
        int t = 0;
        if (tid >= off) t = cs[tid - off];
        __syncthreads();
        cs[tid] += t;
        __syncthreads();
    }
    int run = cs[tid] - sum;
#pragma unroll
    for (int q = 0; q < 4; q++) {
        int idx = base + q;
        if (idx < NBUCKET + 1) bucket_start[idx] = run;
        run += v[q];
    }
}

__global__ __launch_bounds__(256) void scatter_kernel(const int* __restrict__ src,
                                                      const int* __restrict__ dst,
                                                      const int* __restrict__ blkoffT,
                                                      const int* __restrict__ bucket_start,
                                                      int* __restrict__ pairs) {
    __shared__ int cur[NBUCKET];
    int tid = threadIdx.x;
    for (int b = tid; b < NBUCKET; b += 256)
        cur[b] = bucket_start[b] + blkoffT[(size_t)b * 256 + blockIdx.x];
    __syncthreads();
    int base = blockIdx.x * EPB;
    for (int i = tid; i < EPB; i += 256) {
        int d = dst[base + i];
        int s = src[base + i];
        int pos = atomicAdd(&cur[d >> 7], 1);
        pairs[pos] = s | ((d & 127) << 20);
    }
}

__global__ __launch_bounds__(256) void build_csr_kernel(const int* __restrict__ pairs,
                                                        const int* __restrict__ bucket_start,
                                                        int* __restrict__ rowstart,
                                                        int* __restrict__ counts,
                                                        float* __restrict__ dis,
                                                        int* __restrict__ csr_src) {
    __shared__ int lcnt[128];
    __shared__ int lsc[128];
    __shared__ int lcur[128];
    int tid = threadIdx.x;
    int b = blockIdx.x;
    int node_base = b * 128;
    if (tid < 128) lcnt[tid] = 0;
    __syncthreads();
    int rs = bucket_start[b];
    int re = bucket_start[b + 1];
    for (int e = rs + tid; e < re; e += 256)
        atomicAdd(&lcnt[pairs[e] >> 20], 1);
    __syncthreads();
    if (tid < 128) lsc[tid] = lcnt[tid];
    __syncthreads();
    for (int off = 1; off < 128; off <<= 1) {
        int t = 0;
        if (tid < 128 && tid >= off) t = lsc[tid - off];
        __syncthreads();
        if (tid < 128) lsc[tid] += t;
        __syncthreads();
    }
    if (tid < 128) {
        int node = node_base + tid;
        if (node < N_NODES) {
            int startg = rs + lsc[tid] - lcnt[tid];
            rowstart[node] = startg;
            counts[node]   = lcnt[tid];
            dis[node]      = rsqrtf((float)(lcnt[tid] + 1));
            lcur[tid]      = startg;
        }
    }
    __syncthreads();
    for (int e = rs + tid; e < re; e += 256) {
        int v = pairs[e];
        int pos = atomicAdd(&lcur[v >> 20], 1);
        csr_src[pos] = v & 0xFFFFF;
    }
}

// ---------------- MFMA GEMM: Yb(bf16)[N,128] = (Xb @ W) * dis[row] ----------------
// 128-row blocks, full 128x128 W in LDS, XOR-swizzled tiles, 4 waves x (2x8) 16x16 tiles.
// Fragment layouts (mfma_f32_16x16x32_bf16):
//   A: row = lane&15, k = (lane>>4)*8 + j (8 contiguous)
//   B: col = lane&15, k = (lane>>4)*8 + j
//   D: col = lane&15, row = (lane>>4)*4 + reg     [m89-verified]

__global__ __launch_bounds__(256) void gemm_mfma_kernel(const unsigned short* __restrict__ Xb,
                                                        const unsigned short* __restrict__ Wt,
                                                        const float* __restrict__ dis,
                                                        unsigned short* __restrict__ Yb) {
    __shared__ unsigned short Xs[128 * 128];   // 32KB, swizzled
    __shared__ unsigned short Ws[128 * 128];   // 32KB, swizzled
    int tid = threadIdx.x;
    int rowBase = blockIdx.x * 128;

    // stage X tile + W (swizzle: element offset ^= (row&7)<<3, preserves 16B alignment)
    {
        int srow = tid >> 1;
        int sk0  = (tid & 1) * 64;
        bool ok = (rowBase + srow) < N_NODES;
        const unsigned short* xsrc = Xb + (size_t)(rowBase + srow) * 128 + sk0;
        const unsigned short* wsrc = Wt + (size_t)srow * 128 + sk0;
#pragma unroll
        for (int i = 0; i < 8; i++) {
            int k = sk0 + i * 8;
            uint4 xv = ok ? *(const uint4*)(xsrc + i * 8) : make_uint4(0, 0, 0, 0);
            uint4 wv = *(const uint4*)(wsrc + i * 8);
            int eo = (srow * 128 + k) ^ ((srow & 7) << 3);
            *(uint4*)&Xs[eo] = xv;
            *(uint4*)&Ws[eo] = wv;
        }
    }
    __syncthreads();

    int lane = tid & 63;
    int wv_  = tid >> 6;       // wave 0..3 -> rows wv_*32..+32
    int wrow = wv_ * 32;
    int lr   = lane & 15;
    int loct = lane >> 4;

    f32x4 acc[2][8];
#pragma unroll
    for (int a = 0; a < 2; a++)
#pragma unroll
        for (int b = 0; b < 8; b++) acc[a][b] = (f32x4){0.f, 0.f, 0.f, 0.f};

#pragma unroll
    for (int s = 0; s < 4; s++) {
        int kb = s * 32 + loct * 8;
        bf16x8 afr[2];
#pragma unroll
        for (int t2 = 0; t2 < 2; t2++) {
            int row = wrow + t2 * 16 + lr;
            int eo = (row * 128 + kb) ^ ((row & 7) << 3);
            afr[t2] = *(const bf16x8*)&Xs[eo];
        }
#pragma unroll
        for (int tc = 0; tc < 8; tc++) {
            int col = tc * 16 + lr;
            int eo = (col * 128 + kb) ^ ((col & 7) << 3);
            bf16x8 bfr = *(const bf16x8*)&Ws[eo];
            acc[0][tc] = __builtin_amdgcn_mfma_f32_16x16x32_bf16(afr[0], bfr, acc[0][tc], 0, 0, 0);
            acc[1][tc] = __builtin_amdgcn_mfma_f32_16x16x32_bf16(afr[1], bfr, acc[1][tc], 0, 0, 0);
        }
    }

    // epilogue: scale by dis, store bf16
#pragma unroll
    for (int t2 = 0; t2 < 2; t2++) {
        int rbase = rowBase + wrow + t2 * 16 + (lane >> 4) * 4;
        float sc[4];
#pragma unroll
        for (int r = 0; r < 4; r++)
            sc[r] = (rbase + r < N_NODES) ? dis[rbase + r] : 0.f;
#pragma unroll
        for (int tc = 0; tc < 8; tc++) {
            int col = tc * 16 + lr;
#pragma unroll
            for (int r = 0; r < 4; r++) {
                int row = rbase + r;
                if (row < N_NODES)
                    Yb[(size_t)row * 128 + col] = f2bf(acc[t2][tc][r] * sc[r]);
            }
        }
    }
}

// ---------------- Aggregation over bf16 rows, bf16 output ----------------
// out[i] = relu( b + dis[i] * (Hs[i] + sum_{e:dst=i} Hs[src]) )   (Hs pre-scaled by dis)

__global__ __launch_bounds__(256) void aggregate_kernel(const unsigned short* __restrict__ Hs,
                                                        const float* __restrict__ dis,
                                                        const int* __restrict__ rowstart,
                                                        const int* __restrict__ counts,
                                                        const int* __restrict__ csr_src,
                                                        const float* __restrict__ bias,
                                                        unsigned int* __restrict__ OutU) {
    int node = blockIdx.x * 4 + (threadIdx.x >> 6);
    node = __builtin_amdgcn_readfirstlane(node);   // wave-uniform -> scalar loads
    int lane = threadIdx.x & 63;
    if (node >= N_NODES) return;
    int c0 = lane * 2;

    unsigned int ow = *(const unsigned int*)&Hs[(size_t)node * 128 + c0];
    float accx = bf2f((unsigned short)(ow & 0xffffu));
    float accy = bf2f((unsigned short)(ow >> 16));

    int start = rowstart[node];
    int cnt   = counts[node];
    int end = start + cnt;
    int j = start;

    for (; j + 7 < end; j += 8) {
        int s0 = __builtin_nontemporal_load(&csr_src[j]);
        int s1 = __builtin_nontemporal_load(&csr_src[j + 1]);
        int s2 = __builtin_nontemporal_load(&csr_src[j + 2]);
        int s3 = __builtin_nontemporal_load(&csr_src[j + 3]);
        int s4 = __builtin_nontemporal_load(&csr_src[j + 4]);
        int s5 = __builtin_nontemporal_load(&csr_src[j + 5]);
        int s6 = __builtin_nontemporal_load(&csr_src[j + 6]);
        int s7 = __builtin_nontemporal_load(&csr_src[j + 7]);
        unsigned int w0 = *(const unsigned int*)&Hs[(size_t)s0 * 128 + c0];
        unsigned int w1 = *(const unsigned int*)&Hs[(size_t)s1 * 128 + c0];
        unsigned int w2 = *(const unsigned int*)&Hs[(size_t)s2 * 128 + c0];
        unsigned int w3 = *(const unsigned int*)&Hs[(size_t)s3 * 128 + c0];
        unsigned int w4 = *(const unsigned int*)&Hs[(size_t)s4 * 128 + c0];
        unsigned int w5 = *(const unsigned int*)&Hs[(size_t)s5 * 128 + c0];
        unsigned int w6 = *(const unsigned int*)&Hs[(size_t)s6 * 128 + c0];
        unsigned int w7 = *(const unsigned int*)&Hs[(size_t)s7 * 128 + c0];
        accx += ((bf2f((unsigned short)(w0 & 0xffffu)) + bf2f((unsigned short)(w1 & 0xffffu)))
               + (bf2f((unsigned short)(w2 & 0xffffu)) + bf2f((unsigned short)(w3 & 0xffffu))))
              + ((bf2f((unsigned short)(w4 & 0xffffu)) + bf2f((unsigned short)(w5 & 0xffffu)))
               + (bf2f((unsigned short)(w6 & 0xffffu)) + bf2f((unsigned short)(w7 & 0xffffu))));
        accy += ((bf2f((unsigned short)(w0 >> 16)) + bf2f((unsigned short)(w1 >> 16)))
               + (bf2f((unsigned short)(w2 >> 16)) + bf2f((unsigned short)(w3 >> 16))))
              + ((bf2f((unsigned short)(w4 >> 16)) + bf2f((unsigned short)(w5 >> 16)))
               + (bf2f((unsigned short)(w6 >> 16)) + bf2f((unsigned short)(w7 >> 16))));
    }
    for (; j + 1 < end; j += 2) {
        int s0 = __builtin_nontemporal_load(&csr_src[j]);
        int s1 = __builtin_nontemporal_load(&csr_src[j + 1]);
        unsigned int w0 = *(const unsigned int*)&Hs[(size_t)s0 * 128 + c0];
        unsigned int w1 = *(const unsigned int*)&Hs[(size_t)s1 * 128 + c0];
        accx += bf2f((unsigned short)(w0 & 0xffffu)) + bf2f((unsigned short)(w1 & 0xffffu));
        accy += bf2f((unsigned short)(w0 >> 16)) + bf2f((unsigned short)(w1 >> 16));
    }
    if (j < end) {
        int s0 = __builtin_nontemporal_load(&csr_src[j]);
        unsigned int w0 = *(const unsigned int*)&Hs[(size_t)s0 * 128 + c0];
        accx += bf2f((unsigned short)(w0 & 0xffffu));
        accy += bf2f((unsigned short)(w0 >> 16));
    }

    float dsi = dis[node];
    float2 bb = *(const float2*)&bias[c0];
    float rx = fmaxf(fmaf(accx, dsi, bb.x), 0.f);
    float ry = fmaxf(fmaf(accy, dsi, bb.y), 0.f);
    unsigned int pk = (unsigned int)f2bf(rx) | ((unsigned int)f2bf(ry) << 16);
    __builtin_nontemporal_store(pk, &OutU[(size_t)node * 64 + lane]);
}

// ---------------- Final: out = sigmoid(H @ Wr + br)*0.8 + 0.1 ----------------

__global__ __launch_bounds__(256) void final_kernel(const unsigned short* __restrict__ Hb,
                                                    const float* __restrict__ Wr,
                                                    const float* __restrict__ br,
                                                    float* __restrict__ out) {
    __shared__ float hs[16][132];
    __shared__ float ws[128][16];
    int tid = threadIdx.x;
    int rowBase = blockIdx.x * 16;
    {
#pragma unroll
        for (int q = 0; q < 4; q++) {
            int idx = q * 256 + tid;        // 0..1023: 16 rows x 64 bf16-pairs
            int r  = idx >> 6;
            int kp = (idx & 63) * 2;
            unsigned int w = *(const unsigned int*)&Hb[(size_t)(rowBase + r) * 128 + kp];
            hs[r][kp]     = bf2f((unsigned short)(w & 0xffffu));
            hs[r][kp + 1] = bf2f((unsigned short)(w >> 16));
        }
#pragma unroll
        for (int q = 0; q < 8; q++) {
            int idx = q * 256 + tid;
            ws[idx >> 4][idx & 15] = Wr[idx];
        }
    }
    __syncthreads();
    int row = tid >> 4;
    int c   = tid & 15;
    float acc = br[c];
#pragma unroll
    for (int k = 0; k < 128; k++)
        acc = fmaf(hs[row][k], ws[k][c], acc);
    int grow = rowBase + row;
    float sg = 1.f / (1.f + expf(-acc));
    out[(size_t)grow * 16 + c] = 0.8f * sg + 0.1f;
}

// ---------------- Launch ----------------

extern "C" void kernel_launch(void* const* d_in, const int* in_sizes, int n_in,
                              void* d_out, int out_size, void* d_ws, size_t ws_size,
                              hipStream_t stream) {
    const float* x  = (const float*)d_in[0];
    const int*   ei = (const int*)d_in[1];
    const int*   src = ei;
    const int*   dst = ei + N_EDGES;
    const float* W0 = (const float*)d_in[2];
    const float* b0 = (const float*)d_in[3];
    const float* W1 = (const float*)d_in[4];
    const float* b1 = (const float*)d_in[5];
    const float* W2 = (const float*)d_in[6];
    const float* b2 = (const float*)d_in[7];
    const float* Wr = (const float*)d_in[8];
    const float* br = (const float*)d_in[9];
    float* out = (float*)d_out;

    char* ws = (char*)d_ws;
    size_t off = 0;
    auto take = [&](size_t bytes) {
        char* p = ws + off;
        off += (bytes + 255) & ~(size_t)255;
        return p;
    };
    unsigned short* hAb      = (unsigned short*)take((size_t)N_NODES * 128 * 2); // agg out (bf16)
    unsigned short* hBs      = (unsigned short*)take((size_t)N_NODES * 128 * 2); // gemm out (bf16)
    unsigned short* xb       = (unsigned short*)take((size_t)N_NODES * 128 * 2); // x in bf16
    unsigned short* Wt       = (unsigned short*)take(128 * 128 * 2);             // W^T bf16
    int*            counts   = (int*)take((size_t)N_NODES * 4);
    int*            rowstart = (int*)take((size_t)N_NODES * 4);
    float*          dis      = (float*)take((size_t)N_NODES * 4);
    int*            csr_src  = (int*)take((size_t)N_EDGES * 4);
    int*            pairs    = (int*)take((size_t)N_EDGES * 4);
    int*            hist     = (int*)take((size_t)EB * NBUCKET * 4);
    int*            blkoffT  = (int*)take((size_t)NBUCKET * EB * 4);
    int*            btotal   = (int*)take(1024 * 4);
    int*            bstart   = (int*)take(1024 * 4);
    (void)ws_size; (void)in_sizes; (void)n_in; (void)out_size;

    // x -> bf16 (12.8M elements, 4 per thread)
    xconv_kernel<<<12500, 256, 0, stream>>>(x, xb);

    // CSR build: no global atomics, line-local scatters.
    hist_kernel<<<EB, 256, 0, stream>>>(dst, hist);
    scan_hist_kernel<<<NBUCKET, 256, 0, stream>>>(hist, blkoffT, btotal);
    bucket_scan_kernel<<<1, 256, 0, stream>>>(btotal, bstart);
    scatter_kernel<<<EB, 256, 0, stream>>>(src, dst, blkoffT, bstart, pairs);
    build_csr_kernel<<<NBUCKET, 256, 0, stream>>>(pairs, bstart, rowstart, counts, dis, csr_src);

    const float* Wl[3] = {W0, W1, W2};
    const float* bl[3] = {b0, b1, b2};
    const unsigned short* hin = xb;
    for (int l = 0; l < 3; l++) {
        wconv_kernel<<<128, 128, 0, stream>>>(Wl[l], Wt);
        gemm_mfma_kernel<<<(N_NODES + 127) / 128, 256, 0, stream>>>(hin, Wt, dis, hBs);
        aggregate_kernel<<<N_NODES / 4, 256, 0, stream>>>(hBs, dis, rowstart, counts,
                                                          csr_src, bl[l], (unsigned int*)hAb);
        hin = hAb;
    }
    final_kernel<<<N_NODES / 16, 256, 0, stream>>>(hAb, Wr, br, out);
}

// Round 10
// 469.960 us; speedup vs baseline: 6.0468x; 1.0181x over previous
//
#include <hip/hip_runtime.h>
#include <math.h>

#define N_NODES 100000
#define N_EDGES 1600000
#define NBUCKET 782            // ceil(N_NODES/128), 128 nodes per bucket
#define EB      256            // edge-blocks for hist/scatter
#define EPB     6250           // edges per block (EB*EPB == N_EDGES)

typedef __attribute__((ext_vector_type(8))) __bf16 bf16x8;
typedef __attribute__((ext_vector_type(4))) float  f32x4;

// ---------------- bf16 helpers (manual, RNE) ----------------

static __device__ __forceinline__ unsigned short f2bf(float f) {
    unsigned int u = __float_as_uint(f);
    unsigned int r = (u + 0x7FFFu + ((u >> 16) & 1u)) >> 16;
    return (unsigned short)r;
}
static __device__ __forceinline__ float bf2f(unsigned short h) {
    return __uint_as_float(((unsigned int)h) << 16);
}

// Wt[n][k] = bf16(W[k][n])
__global__ void wconv_kernel(const float* __restrict__ W, unsigned short* __restrict__ Wt) {
    int n = blockIdx.x;
    int k = threadIdx.x;
    Wt[n * 128 + k] = f2bf(W[k * 128 + n]);
}

// ---------------- CSR build: contention-free counting sort ----------------
// Record pack: src in bits 0..16, (dst&127) in bits 20..26.

__global__ __launch_bounds__(256) void hist_kernel(const int* __restrict__ dst,
                                                   int* __restrict__ hist /*[EB][NBUCKET]*/) {
    __shared__ int h[NBUCKET];
    int tid = threadIdx.x;
    for (int b = tid; b < NBUCKET; b += 256) h[b] = 0;
    __syncthreads();
    int base = blockIdx.x * EPB;
    for (int i = tid; i < EPB; i += 256)
        atomicAdd(&h[dst[base + i] >> 7], 1);
    __syncthreads();
    int* hrow = hist + (size_t)blockIdx.x * NBUCKET;
    for (int b = tid; b < NBUCKET; b += 256) hrow[b] = h[b];
}

__global__ __launch_bounds__(256) void scan_hist_kernel(const int* __restrict__ hist,
                                                        int* __restrict__ blkoffT,
                                                        int* __restrict__ btotal) {
    __shared__ int s[256];
    int b = blockIdx.x;
    int k = threadIdx.x;
    int v = hist[(size_t)k * NBUCKET + b];
    s[k] = v;
    __syncthreads();
    for (int off = 1; off < 256; off <<= 1) {
        int t = 0;
        if (k >= off) t = s[k - off];
        __syncthreads();
        s[k] += t;
        __syncthreads();
    }
    blkoffT[(size_t)b * 256 + k] = s[k] - v;
    if (k == 255) btotal[b] = s[255];
}

__global__ __launch_bounds__(256) void bucket_scan_kernel(const int* __restrict__ btotal,
                                                          int* __restrict__ bucket_start) {
    __shared__ int cs[256];
    int tid = threadIdx.x;
    int base = tid * 4;
    int v[4];
    int sum = 0;
#pragma unroll
    for (int q = 0; q < 4; q++) {
        int idx = base + q;
        v[q] = (idx < NBUCKET) ? btotal[idx] : 0;
        sum += v[q];
    }
    cs[tid] = sum;
    __syncthreads();
    for (int off = 1; off < 256; off <<= 1) {
        int t = 0;
        if (tid >= off) t = cs[tid - off];
        __syncthreads();
        cs[tid] += t;
        __syncthreads();
    }
    int run = cs[tid] - sum;
#pragma unroll
    for (int q = 0; q < 4; q++) {
        int idx = base + q;
        if (idx < NBUCKET + 1) bucket_start[idx] = run;
        run += v[q];
    }
}

__global__ __launch_bounds__(256) void scatter_kernel(const int* __restrict__ src,
                                                      const int* __restrict__ dst,
                                                      const int* __restrict__ blkoffT,
                                                      const int* __restrict__ bucket_start,
                                                      int* __restrict__ pairs) {
    __shared__ int cur[NBUCKET];
    int tid = threadIdx.x;
    for (int b = tid; b < NBUCKET; b += 256)
        cur[b] = bucket_start[b] + blkoffT[(size_t)b * 256 + blockIdx.x];
    __syncthreads();
    int base = blockIdx.x * EPB;
    for (int i = tid; i < EPB; i += 256) {
        int d = dst[base + i];
        int s = src[base + i];
        int pos = atomicAdd(&cur[d >> 7], 1);
        pairs[pos] = s | ((d & 127) << 20);
    }
}

__global__ __launch_bounds__(256) void build_csr_kernel(const int* __restrict__ pairs,
                                                        const int* __restrict__ bucket_start,
                                                        int* __restrict__ rowstart,
                                                        int* __restrict__ counts,
                                                        float* __restrict__ dis,
                                                        int* __restrict__ csr_src) {
    __shared__ int lcnt[128];
    __shared__ int lsc[128];
    __shared__ int lcur[128];
    int tid = threadIdx.x;
    int b = blockIdx.x;
    int node_base = b * 128;
    if (tid < 128) lcnt[tid] = 0;
    __syncthreads();
    int rs = bucket_start[b];
    int re = bucket_start[b + 1];
    for (int e = rs + tid; e < re; e += 256)
        atomicAdd(&lcnt[pairs[e] >> 20], 1);
    __syncthreads();
    if (tid < 128) lsc[tid] = lcnt[tid];
    __syncthreads();
    for (int off = 1; off < 128; off <<= 1) {
        int t = 0;
        if (tid < 128 && tid >= off) t = lsc[tid - off];
        __syncthreads();
        if (tid < 128) lsc[tid] += t;
        __syncthreads();
    }
    if (tid < 128) {
        int node = node_base + tid;
        if (node < N_NODES) {
            int startg = rs + lsc[tid] - lcnt[tid];
            rowstart[node] = startg;
            counts[node]   = lcnt[tid];
            dis[node]      = rsqrtf((float)(lcnt[tid] + 1));
            lcur[tid]      = startg;
        }
    }
    __syncthreads();
    for (int e = rs + tid; e < re; e += 256) {
        int v = pairs[e];
        int pos = atomicAdd(&lcur[v >> 20], 1);
        csr_src[pos] = v & 0xFFFFF;
    }
}

// ---------------- MFMA GEMM (no LDS): Yb(bf16)[N,128] = (X @ W) * dis[row] ----------------
// 128-row blocks, 4 waves x (2x8) 16x16 tiles; fragments loaded straight from global.
// Per (s,t2): wave reads 16 rows x 64B -> full aligned cache lines. W^T (32KB) is L1/L2-hot.
// Fragment layouts (mfma_f32_16x16x32_bf16):
//   A: row = lane&15, k = (lane>>4)*8 + j;  B: col = lane&15, same k
//   D: col = lane&15, row = (lane>>4)*4 + reg     [m89-verified, r8-passed]

template <bool FP32IN>
__global__ __launch_bounds__(256) void gemm_mfma_kernel(const void* __restrict__ Xin,
                                                        const unsigned short* __restrict__ Wt,
                                                        const float* __restrict__ dis,
                                                        unsigned short* __restrict__ Yb) {
    int tid = threadIdx.x;
    int rowBase = blockIdx.x * 128;
    int lane = tid & 63;
    int wv_  = tid >> 6;       // wave 0..3 -> rows wv_*32..+32
    int wrow = wv_ * 32;
    int lr   = lane & 15;
    int loct = lane >> 4;

    const float*          Xf = (const float*)Xin;
    const unsigned short* Xb = (const unsigned short*)Xin;

    f32x4 acc[2][8];
#pragma unroll
    for (int a = 0; a < 2; a++)
#pragma unroll
        for (int b = 0; b < 8; b++) acc[a][b] = (f32x4){0.f, 0.f, 0.f, 0.f};

#pragma unroll
    for (int s = 0; s < 4; s++) {
        int kb = s * 32 + loct * 8;
        bf16x8 afr[2];
#pragma unroll
        for (int t2 = 0; t2 < 2; t2++) {
            int row = rowBase + wrow + t2 * 16 + lr;
            if (row < N_NODES) {
                if (FP32IN) {
                    float4 v0 = *(const float4*)&Xf[(size_t)row * 128 + kb];
                    float4 v1 = *(const float4*)&Xf[(size_t)row * 128 + kb + 4];
                    union { unsigned short u[8]; bf16x8 v; } cv;
                    cv.u[0] = f2bf(v0.x); cv.u[1] = f2bf(v0.y);
                    cv.u[2] = f2bf(v0.z); cv.u[3] = f2bf(v0.w);
                    cv.u[4] = f2bf(v1.x); cv.u[5] = f2bf(v1.y);
                    cv.u[6] = f2bf(v1.z); cv.u[7] = f2bf(v1.w);
                    afr[t2] = cv.v;
                } else {
                    afr[t2] = *(const bf16x8*)&Xb[(size_t)row * 128 + kb];
                }
            } else {
                union { unsigned short u[8]; bf16x8 v; } z;
#pragma unroll
                for (int j = 0; j < 8; j++) z.u[j] = 0;
                afr[t2] = z.v;
            }
        }
#pragma unroll
        for (int tc = 0; tc < 8; tc++) {
            int col = tc * 16 + lr;
            bf16x8 bfr = *(const bf16x8*)&Wt[(size_t)col * 128 + kb];
            acc[0][tc] = __builtin_amdgcn_mfma_f32_16x16x32_bf16(afr[0], bfr, acc[0][tc], 0, 0, 0);
            acc[1][tc] = __builtin_amdgcn_mfma_f32_16x16x32_bf16(afr[1], bfr, acc[1][tc], 0, 0, 0);
        }
    }

    // epilogue: scale by dis, store bf16
#pragma unroll
    for (int t2 = 0; t2 < 2; t2++) {
        int rbase = rowBase + wrow + t2 * 16 + (lane >> 4) * 4;
        float sc[4];
#pragma unroll
        for (int r = 0; r < 4; r++)
            sc[r] = (rbase + r < N_NODES) ? dis[rbase + r] : 0.f;
#pragma unroll
        for (int tc = 0; tc < 8; tc++) {
            int col = tc * 16 + lr;
#pragma unroll
            for (int r = 0; r < 4; r++) {
                int row = rbase + r;
                if (row < N_NODES)
                    Yb[(size_t)row * 128 + col] = f2bf(acc[t2][tc][r] * sc[r]);
            }
        }
    }
}

// ---------------- Aggregation over bf16 rows, bf16 output ----------------
// out[i] = relu( b + dis[i] * (Hs[i] + sum_{e:dst=i} Hs[src]) )   (Hs pre-scaled by dis)

__global__ __launch_bounds__(256) void aggregate_kernel(const unsigned short* __restrict__ Hs,
                                                        const float* __restrict__ dis,
                                                        const int* __restrict__ rowstart,
                                                        const int* __restrict__ counts,
                                                        const int* __restrict__ csr_src,
                                                        const float* __restrict__ bias,
                                                        unsigned int* __restrict__ OutU) {
    int node = blockIdx.x * 4 + (threadIdx.x >> 6);
    node = __builtin_amdgcn_readfirstlane(node);   // wave-uniform -> scalar loads
    int lane = threadIdx.x & 63;
    if (node >= N_NODES) return;
    int c0 = lane * 2;

    unsigned int ow = *(const unsigned int*)&Hs[(size_t)node * 128 + c0];
    float accx = bf2f((unsigned short)(ow & 0xffffu));
    float accy = bf2f((unsigned short)(ow >> 16));

    int start = rowstart[node];
    int cnt   = counts[node];
    int end = start + cnt;
    int j = start;

    for (; j + 7 < end; j += 8) {
        int s0 = __builtin_nontemporal_load(&csr_src[j]);
        int s1 = __builtin_nontemporal_load(&csr_src[j + 1]);
        int s2 = __builtin_nontemporal_load(&csr_src[j + 2]);
        int s3 = __builtin_nontemporal_load(&csr_src[j + 3]);
        int s4 = __builtin_nontemporal_load(&csr_src[j + 4]);
        int s5 = __builtin_nontemporal_load(&csr_src[j + 5]);
        int s6 = __builtin_nontemporal_load(&csr_src[j + 6]);
        int s7 = __builtin_nontemporal_load(&csr_src[j + 7]);
        unsigned int w0 = *(const unsigned int*)&Hs[(size_t)s0 * 128 + c0];
        unsigned int w1 = *(const unsigned int*)&Hs[(size_t)s1 * 128 + c0];
        unsigned int w2 = *(const unsigned int*)&Hs[(size_t)s2 * 128 + c0];
        unsigned int w3 = *(const unsigned int*)&Hs[(size_t)s3 * 128 + c0];
        unsigned int w4 = *(const unsigned int*)&Hs[(size_t)s4 * 128 + c0];
        unsigned int w5 = *(const unsigned int*)&Hs[(size_t)s5 * 128 + c0];
        unsigned int w6 = *(const unsigned int*)&Hs[(size_t)s6 * 128 + c0];
        unsigned int w7 = *(const unsigned int*)&Hs[(size_t)s7 * 128 + c0];
        accx += ((bf2f((unsigned short)(w0 & 0xffffu)) + bf2f((unsigned short)(w1 & 0xffffu)))
               + (bf2f((unsigned short)(w2 & 0xffffu)) + bf2f((unsigned short)(w3 & 0xffffu))))
              + ((bf2f((unsigned short)(w4 & 0xffffu)) + bf2f((unsigned short)(w5 & 0xffffu)))
               + (bf2f((unsigned short)(w6 & 0xffffu)) + bf2f((unsigned short)(w7 & 0xffffu))));
        accy += ((bf2f((unsigned short)(w0 >> 16)) + bf2f((unsigned short)(w1 >> 16)))
               + (bf2f((unsigned short)(w2 >> 16)) + bf2f((unsigned short)(w3 >> 16))))
              + ((bf2f((unsigned short)(w4 >> 16)) + bf2f((unsigned short)(w5 >> 16)))
               + (bf2f((unsigned short)(w6 >> 16)) + bf2f((unsigned short)(w7 >> 16))));
    }
    for (; j + 1 < end; j += 2) {
        int s0 = __builtin_nontemporal_load(&csr_src[j]);
        int s1 = __builtin_nontemporal_load(&csr_src[j + 1]);
        unsigned int w0 = *(const unsigned int*)&Hs[(size_t)s0 * 128 + c0];
        unsigned int w1 = *(const unsigned int*)&Hs[(size_t)s1 * 128 + c0];
        accx += bf2f((unsigned short)(w0 & 0xffffu)) + bf2f((unsigned short)(w1 & 0xffffu));
        accy += bf2f((unsigned short)(w0 >> 16)) + bf2f((unsigned short)(w1 >> 16));
    }
    if (j < end) {
        int s0 = __builtin_nontemporal_load(&csr_src[j]);
        unsigned int w0 = *(const unsigned int*)&Hs[(size_t)s0 * 128 + c0];
        accx += bf2f((unsigned short)(w0 & 0xffffu));
        accy += bf2f((unsigned short)(w0 >> 16));
    }

    float dsi = dis[node];
    float2 bb = *(const float2*)&bias[c0];
    float rx = fmaxf(fmaf(accx, dsi, bb.x), 0.f);
    float ry = fmaxf(fmaf(accy, dsi, bb.y), 0.f);
    unsigned int pk = (unsigned int)f2bf(rx) | ((unsigned int)f2bf(ry) << 16);
    __builtin_nontemporal_store(pk, &OutU[(size_t)node * 64 + lane]);
}

// ---------------- Final: out = sigmoid(H @ Wr + br)*0.8 + 0.1 ----------------

__global__ __launch_bounds__(256) void final_kernel(const unsigned short* __restrict__ Hb,
                                                    const float* __restrict__ Wr,
                                                    const float* __restrict__ br,
                                                    float* __restrict__ out) {
    __shared__ float hs[16][132];
    __shared__ float ws[128][16];
    int tid = threadIdx.x;
    int rowBase = blockIdx.x * 16;
    {
#pragma unroll
        for (int q = 0; q < 4; q++) {
            int idx = q * 256 + tid;        // 0..1023: 16 rows x 64 bf16-pairs
            int r  = idx >> 6;
            int kp = (idx & 63) * 2;
            unsigned int w = *(const unsigned int*)&Hb[(size_t)(rowBase + r) * 128 + kp];
            hs[r][kp]     = bf2f((unsigned short)(w & 0xffffu));
            hs[r][kp + 1] = bf2f((unsigned short)(w >> 16));
        }
#pragma unroll
        for (int q = 0; q < 8; q++) {
            int idx = q * 256 + tid;
            ws[idx >> 4][idx & 15] = Wr[idx];
        }
    }
    __syncthreads();
    int row = tid >> 4;
    int c   = tid & 15;
    float acc = br[c];
#pragma unroll
    for (int k = 0; k < 128; k++)
        acc = fmaf(hs[row][k], ws[k][c], acc);
    int grow = rowBase + row;
    float sg = 1.f / (1.f + expf(-acc));
    out[(size_t)grow * 16 + c] = 0.8f * sg + 0.1f;
}

// ---------------- Launch ----------------

extern "C" void kernel_launch(void* const* d_in, const int* in_sizes, int n_in,
                              void* d_out, int out_size, void* d_ws, size_t ws_size,
                              hipStream_t stream) {
    const float* x  = (const float*)d_in[0];
    const int*   ei = (const int*)d_in[1];
    const int*   src = ei;
    const int*   dst = ei + N_EDGES;
    const float* W0 = (const float*)d_in[2];
    const float* b0 = (const float*)d_in[3];
    const float* W1 = (const float*)d_in[4];
    const float* b1 = (const float*)d_in[5];
    const float* W2 = (const float*)d_in[6];
    const float* b2 = (const float*)d_in[7];
    const float* Wr = (const float*)d_in[8];
    const float* br = (const float*)d_in[9];
    float* out = (float*)d_out;

    char* ws = (char*)d_ws;
    size_t off = 0;
    auto take = [&](size_t bytes) {
        char* p = ws + off;
        off += (bytes + 255) & ~(size_t)255;
        return p;
    };
    unsigned short* hAb      = (unsigned short*)take((size_t)N_NODES * 128 * 2); // agg out (bf16)
    unsigned short* hBs      = (unsigned short*)take((size_t)N_NODES * 128 * 2); // gemm out (bf16)
    unsigned short* Wt       = (unsigned short*)take(128 * 128 * 2);             // W^T bf16
    int*            counts   = (int*)take((size_t)N_NODES * 4);
    int*            rowstart = (int*)take((size_t)N_NODES * 4);
    float*          dis      = (float*)take((size_t)N_NODES * 4);
    int*            csr_src  = (int*)take((size_t)N_EDGES * 4);
    int*            pairs    = (int*)take((size_t)N_EDGES * 4);
    int*            hist     = (int*)take((size_t)EB * NBUCKET * 4);
    int*            blkoffT  = (int*)take((size_t)NBUCKET * EB * 4);
    int*            btotal   = (int*)take(1024 * 4);
    int*            bstart   = (int*)take(1024 * 4);
    (void)ws_size; (void)in_sizes; (void)n_in; (void)out_size;

    // CSR build: no global atomics, line-local scatters.
    hist_kernel<<<EB, 256, 0, stream>>>(dst, hist);
    scan_hist_kernel<<<NBUCKET, 256, 0, stream>>>(hist, blkoffT, btotal);
    bucket_scan_kernel<<<1, 256, 0, stream>>>(btotal, bstart);
    scatter_kernel<<<EB, 256, 0, stream>>>(src, dst, blkoffT, bstart, pairs);
    build_csr_kernel<<<NBUCKET, 256, 0, stream>>>(pairs, bstart, rowstart, counts, dis, csr_src);

    const float* Wl[3] = {W0, W1, W2};
    const float* bl[3] = {b0, b1, b2};
    int gemmBlocks = (N_NODES + 127) / 128;   // 782
    for (int l = 0; l < 3; l++) {
        wconv_kernel<<<128, 128, 0, stream>>>(Wl[l], Wt);
        if (l == 0)
            gemm_mfma_kernel<true><<<gemmBlocks, 256, 0, stream>>>(x, Wt, dis, hBs);
        else
            gemm_mfma_kernel<false><<<gemmBlocks, 256, 0, stream>>>(hAb, Wt, dis, hBs);
        aggregate_kernel<<<N_NODES / 4, 256, 0, stream>>>(hBs, dis, rowstart, counts,
                                                          csr_src, bl[l], (unsigned int*)hAb);
    }
    final_kernel<<<N_NODES / 16, 256, 0, stream>>>(hAb, Wr, br, out);
}